// Round 16
// baseline (108.461 us; speedup 1.0000x reference)
//
#include <hip/hip_runtime.h>
#include <stdint.h>

#define NROWS 4096
#define NHID 1024
#define CC0 1675
#define CC1 5025
#define HEADSZ 1677
#define PD0 256
#define PD1 64
#define TSZ0 3350
#define TSZ1 45232
#define HPN (HEADSZ + PD0 + PD1)   // 1997: head + proj0 + proj1 fused B
#define NT1 354                    // ceil(45232/128)
#define TPC1 15
#define L2E 1.4426950408889634f
#define LN2 0.6931471805599453f

// fused_mid grid segmentation: proj GEMM + w0/w1 conversion only
#define NB_PJ 96         // 3 colChunks x 32 rowBlks (proj, N=320)
#define NB_CW 512        // w0/w1 bf16 conversion (grid-stride)
#define NB_MID (NB_PJ + NB_CW)

// fused_tail grid segmentation (segment starts/sizes divisible by 8)
#define NB_HD 448        // 14 colChunks x 32 rowBlks (head-sum, N=1677)
#define NB_C1 768        // 24 colChunks(tpc=15) x 32 rowBlks
#define NB_C0 864        // 27 colChunks x 32 rowBlks (compaction early-exit)
#define NB_TG 128        // 4096 rows / (4 waves x 8 rows)
#define NB_TAIL (NB_HD + NB_C1 + NB_C0 + NB_TG)

typedef __attribute__((ext_vector_type(8))) __bf16 bf16x8;
typedef __attribute__((ext_vector_type(4))) float f32x4;

__device__ __forceinline__ unsigned short f2bf(float f) {
  union { float f; uint32_t u; } v; v.f = f;
  return (unsigned short)((v.u + 0x7FFFu + ((v.u >> 16) & 1u)) >> 16);
}
__device__ __forceinline__ float bfl(uint32_t u) {
  union { uint32_t u; float f; } v; v.u = u << 16; return v.f;
}
__device__ __forceinline__ float bfh(uint32_t u) {
  union { uint32_t u; float f; } v; v.u = u & 0xFFFF0000u; return v.f;
}
__device__ __forceinline__ float bf1(unsigned short u) {
  union { uint32_t u; float f; } v; v.u = ((uint32_t)u) << 16; return v.f;
}
#define EXP2(x) __builtin_amdgcn_exp2f(x)

// ---- conversion ranges (float4 units, compile-time) ----
#define CV1 1048576                  // x
#define CV2 1477888                  // head_w (xL2E)
#define CV3 1543424                  // proj0
#define CV4 1559808                  // proj1
#define CV5 1774208                  // w0 (xL2E)
#define CV6 2497920                  // w1 (xL2E)
#define CVW0 (CV5 - CV4)             // 214400
#define CVW  (CV6 - CV4)             // 938112

// conv for x, head_w, proj0, proj1 (blocks 0-1023) + row compaction
// (block 1024: builds idx/pos lists for cluster-0/1 rows, deterministic).
__global__ void conv_part(const float* __restrict__ x, const float* __restrict__ hw,
                          const float* __restrict__ p0, const float* __restrict__ p1,
                          unsigned short* __restrict__ dst,
                          const int* __restrict__ y,
                          int* __restrict__ idx0, int* __restrict__ pos0,
                          int* __restrict__ idx1, int* __restrict__ pos1,
                          int* __restrict__ n01) {
  if (blockIdx.x == 1024) {
    __shared__ int sc0[256], sc1[256], nsh[2];
    int t = threadIdx.x;
    int yl[16];
    int c0 = 0, c1 = 0;
#pragma unroll
    for (int k = 0; k < 16; ++k) {
      int yv = y[t * 16 + k];
      yl[k] = yv;
      c0 += (yv >= CC0 && yv < CC1);
      c1 += (yv >= CC1);
    }
    sc0[t] = c0; sc1[t] = c1;
    __syncthreads();
    if (t == 0) {
      int a0 = 0, a1 = 0;
      for (int i = 0; i < 256; ++i) {
        int v0 = sc0[i]; sc0[i] = a0; a0 += v0;
        int v1 = sc1[i]; sc1[i] = a1; a1 += v1;
      }
      n01[0] = a0; n01[1] = a1; nsh[0] = a0; nsh[1] = a1;
    }
    __syncthreads();
    int p0c = sc0[t], p1c = sc1[t];
#pragma unroll
    for (int k = 0; k < 16; ++k) {
      int n = t * 16 + k, yv = yl[k];
      if (yv >= CC0 && yv < CC1) { idx0[p0c] = n; pos0[n] = p0c; ++p0c; }
      else if (yv >= CC1)        { idx1[p1c] = n; pos1[n] = p1c; ++p1c; }
    }
    for (int j = nsh[0] + t; j < NROWS; j += 256) idx0[j] = 0;
    for (int j = nsh[1] + t; j < NROWS; j += 256) idx1[j] = 0;
    return;
  }
  const int stride = 1024 * 256;
  for (int i = blockIdx.x * 256 + threadIdx.x; i < CV4; i += stride) {
    const float* src; int off; float sc;
    if (i < CV1)      { src = x;  off = i;       sc = 1.f; }
    else if (i < CV2) { src = hw; off = i - CV1; sc = L2E; }
    else if (i < CV3) { src = p0; off = i - CV2; sc = 1.f; }
    else              { src = p1; off = i - CV3; sc = 1.f; }
    float4 v = reinterpret_cast<const float4*>(src)[off];
    ushort4 o;
    o.x = f2bf(v.x * sc); o.y = f2bf(v.y * sc);
    o.z = f2bf(v.z * sc); o.w = f2bf(v.w * sc);
    reinterpret_cast<ushort4*>(dst)[i] = o;
  }
}

#define GLOAD(g, l) __builtin_amdgcn_global_load_lds( \
    (const __attribute__((address_space(1))) uint32_t*)(const void*)(g), \
    (__attribute__((address_space(3))) uint32_t*)(void*)(l), 16, 0, 0)

// Involution swizzle on byte offsets within an 8KB [128][32]-bf16 tile:
// XOR bits 4-6 with bits 7-9. Bank-verified (round 2): conflicts 0.
#define SWZB(L) ((L) ^ ((((L) >> 7) & 7) << 4))

// --------------- 256-thread GEMM core (3-buffer counted ring) --------------
// gidx: optional A-row gather (compacted row lists); nullptr = identity.
__device__ __forceinline__
void gemm_core(const unsigned short* __restrict__ A, int lda,
               const unsigned short* __restrict__ B, int ldb,
               int N, int K, int tile0, int tile1, int brow,
               const float* __restrict__ bias,
               float* __restrict__ sum_out,
               unsigned short* __restrict__ Cout, int ldc, int coutStart,
               unsigned short* AsB, unsigned short* BsB,
               const int* __restrict__ gidx) {
  const int tid = threadIdx.x;
  const int lane = tid & 63;
  const int wid = tid >> 6;
  const int wrow = (wid >> 1) * 64;
  const int wcol = (wid & 1) * 64;
  const int lr = lane & 15, lg = lane >> 4;
  const int nsteps = (tile1 - tile0) * (K >> 5);
  const int rowBase = brow + wrow;

  // A source rows for this thread's 2 staging chunks (constant across steps)
  int arowc[2];
#pragma unroll
  for (int c = 0; c < 2; ++c) {
    int g = wid * 128 + c * 64 + lane;
    int S = SWZB(g * 16);
    int row = S >> 6;
    arowc[c] = gidx ? gidx[brow + row] : brow + row;
  }

  float sacc[4][4];
#pragma unroll
  for (int m = 0; m < 4; ++m)
#pragma unroll
    for (int r = 0; r < 4; ++r) sacc[m][r] = 0.f;

  auto stage = [&](int b, int tt, int kk) {
#pragma unroll
    for (int c = 0; c < 2; ++c) {
      int g = wid * 128 + c * 64 + lane;
      int L = g * 16;
      int S = SWZB(L);
      int row = S >> 6, ko = (S >> 4) & 3;
      GLOAD(A + (size_t)arowc[c] * lda + kk + ko * 8, (char*)AsB + b * 8192 + L);
      int bsrc = tt * 128 + row; bsrc = bsrc < N ? bsrc : N - 1;
      GLOAD(B + (size_t)bsrc * ldb + kk + ko * 8, (char*)BsB + b * 8192 + L);
    }
  };

  f32x4 acc[4][4];
#pragma unroll
  for (int m = 0; m < 4; ++m)
#pragma unroll
    for (int n = 0; n < 4; ++n) acc[m][n] = (f32x4){0.f, 0.f, 0.f, 0.f};

  int tp = tile0, kp = 0;
  auto adv = [&](int& t, int& k) { k += 32; if (k == K) { k = 0; ++t; } };
  stage(0, tp, kp); adv(tp, kp);
  if (nsteps > 1) { stage(1, tp, kp); adv(tp, kp); }

  int tile = tile0, k0 = 0;
  for (int s = 0; s < nsteps; ++s) {
    if (s + 1 < nsteps) asm volatile("s_waitcnt vmcnt(4)" ::: "memory");
    else                asm volatile("s_waitcnt vmcnt(0)" ::: "memory");
    __builtin_amdgcn_s_barrier();
    if (s + 2 < nsteps) { stage((s + 2) % 3, tp, kp); adv(tp, kp); }

    const int cur = s % 3;
    int k0n = k0 + 32, tn = tile;
    if (k0n == K) { k0n = 0; tn = tile + 1; }

    bf16x8 af[4], bfv[4];
#pragma unroll
    for (int m = 0; m < 4; ++m)
      af[m] = *(const bf16x8*)((const char*)AsB + cur * 8192 +
                               SWZB((wrow + m * 16 + lr) * 64 + lg * 16));
#pragma unroll
    for (int n = 0; n < 4; ++n)
      bfv[n] = *(const bf16x8*)((const char*)BsB + cur * 8192 +
                                SWZB((wcol + n * 16 + lr) * 64 + lg * 16));
#pragma unroll
    for (int m = 0; m < 4; ++m)
#pragma unroll
      for (int n = 0; n < 4; ++n)
        acc[m][n] = __builtin_amdgcn_mfma_f32_16x16x32_bf16(af[m], bfv[n], acc[m][n], 0, 0, 0);

    if (tn != tile) {
      const int cb = tile * 128 + wcol;
#pragma unroll
      for (int m = 0; m < 4; ++m)
#pragma unroll
        for (int n = 0; n < 4; ++n) {
#pragma unroll
          for (int r = 0; r < 4; ++r) {
            int col = cb + n * 16 + lr;
            if (col < N) {
              float v = acc[m][n][r];
              if (Cout && col >= coutStart) {
                int row = rowBase + m * 16 + lg * 4 + r;
                Cout[(size_t)row * ldc + (col - coutStart)] = f2bf(v);
              } else {
                if (bias) v = fmaf(bias[col], L2E, v);  // v already log2e-scaled
                sacc[m][r] += EXP2(v);
              }
            }
          }
          acc[m][n] = (f32x4){0.f, 0.f, 0.f, 0.f};
        }
    }
    tile = tn; k0 = k0n;
  }

#pragma unroll
  for (int m = 0; m < 4; ++m)
#pragma unroll
    for (int r = 0; r < 4; ++r) {
      float s = sacc[m][r];
      s += __shfl_xor(s, 1); s += __shfl_xor(s, 2);
      s += __shfl_xor(s, 4); s += __shfl_xor(s, 8);
      if (lr == 0) atomicAdd(&sum_out[rowBase + m * 16 + lg * 4 + r], s);
    }
}

// ---- fused mid: proj GEMM | w0/w1 conversion (256 thr) --------------------
__global__ __launch_bounds__(256, 3)
void fused_mid(const unsigned short* __restrict__ xb,
               const unsigned short* __restrict__ hpb,
               unsigned short* __restrict__ hb,
               float* __restrict__ dm,
               const float* __restrict__ w0f, const float* __restrict__ w1f,
               unsigned short* __restrict__ dstAll) {
  __shared__ __align__(16) unsigned short lds[6 * 4096];   // 48KB union
  const int bid = blockIdx.x;

  if (bid < NB_PJ) {
    // proj: hb = xb @ [proj0;proj1]^T, N=320, K=1024
    const int cpx = NB_PJ >> 3;          // 12
    const int sid = (bid & 7) * cpx + (bid >> 3);
    const int rowBlk = sid & 31;
    const int colChunk = sid >> 5;       // [0,3)
    gemm_core(xb, NHID, hpb + (size_t)HEADSZ * NHID, NHID, PD0 + PD1, NHID,
              colChunk, colChunk + 1, rowBlk * 128,
              nullptr, dm, hb, PD0 + PD1, 0, lds, lds + 3 * 4096, nullptr);
    return;
  }

  // w0/w1 f32->bf16 conversion (xL2E), grid-stride
  {
    const int b2 = bid - NB_PJ;          // [0,512)
    const int stride = NB_CW * 256;
    for (int i = b2 * 256 + (int)threadIdx.x; i < CVW; i += stride) {
      const float* src; int off;
      if (i < CVW0) { src = w0f; off = i; }
      else          { src = w1f; off = i - CVW0; }
      float4 v = reinterpret_cast<const float4*>(src)[off];
      ushort4 o;
      o.x = f2bf(v.x * L2E); o.y = f2bf(v.y * L2E);
      o.z = f2bf(v.z * L2E); o.w = f2bf(v.w * L2E);
      reinterpret_cast<ushort4*>(dstAll)[CV4 + i] = o;
    }
  }
}

// -- fused tail: head-sum | c1 (compacted) | c0 (compacted) | target --------
// Head uses rowBlk-major XCD swizzle (A panels L2-local; round-12 verified).
// c0/c1 rows gathered through idx0/idx1; blocks past compacted count exit.
__global__ __launch_bounds__(256, 3)
void fused_tail(const unsigned short* __restrict__ hb,
                const unsigned short* __restrict__ w0b,
                const unsigned short* __restrict__ w1b,
                const unsigned short* __restrict__ xb,
                const unsigned short* __restrict__ hwb,
                const float* __restrict__ head_b,
                const int* __restrict__ y,
                const int* __restrict__ idx0, const int* __restrict__ idx1,
                const int* __restrict__ n01,
                float* __restrict__ hs,
                float* __restrict__ s0, float* __restrict__ s1,
                float* __restrict__ ht, float* __restrict__ tc) {
  __shared__ __align__(16) unsigned short lds[6 * 4096];   // 48KB union
  const int bid = blockIdx.x;

  if (bid < NB_HD) {
    // ---- head exp2-sum: xb @ head_w^T, N=1677, K=1024 (32-step ring) ----
    const int xcd = bid & 7;
    const int local = bid >> 3;          // [0,56)
    const int rowBlk = xcd * 4 + local / 14;
    const int colChunk = local % 14;
    gemm_core(xb, NHID, hwb, NHID, HEADSZ, NHID, colChunk, colChunk + 1,
              rowBlk * 128, head_b, hs, nullptr, 0, 0,
              lds, lds + 3 * 4096, nullptr);
    return;
  }

  if (bid < NB_HD + NB_C1) {
    // ---- cluster 1: hb[:,256:] @ w1^T (compacted rows), K=64 ----
    const int b1 = bid - NB_HD;
    const int tid = threadIdx.x;
    const int lane = tid & 63;
    const int wid = tid >> 6;
    const int lr = lane & 15, lg = lane >> 4;
    const int cpx = NB_C1 >> 3;        // 96
    const int sid = (b1 & 7) * cpx + (b1 >> 3);
    const int rowBlk = sid & 31;
    const int colChunk = sid >> 5;     // [0,24)
    if (rowBlk * 128 >= n01[1]) return;          // compaction early-exit
    const int rowBase = rowBlk * 128 + (wid >> 1) * 64;
    const int wcol = (wid & 1) * 64;
    const int tile0 = colChunk * TPC1;
    const int tile1 = min(tile0 + TPC1, NT1);
    const int nt = tile1 - tile0;

    int colOff[4], srcOff[4];
#pragma unroll
    for (int c = 0; c < 4; ++c) {
      int L = (c * 256 + tid) * 16;
      int S = L ^ (((L >> 7) & 7) << 4);
      colOff[c] = S >> 7;
      srcOff[c] = (S & 127) >> 1;
    }
    auto stage = [&](int b, int t) {
#pragma unroll
      for (int c = 0; c < 4; ++c) {
        int gc = t * 128 + colOff[c];
        gc = gc < TSZ1 ? gc : TSZ1 - 1;
        GLOAD(w1b + (size_t)gc * PD1 + srcOff[c],
              (char*)lds + b * 16384 + (c * 256 + tid) * 16);
      }
    };

    bf16x8 af[4][2];
#pragma unroll
    for (int m = 0; m < 4; ++m) {
      int ridx = idx1[rowBase + m * 16 + lr];    // gathered A row
      const unsigned short* p = hb + PD0 +
          (size_t)ridx * (PD0 + PD1) + lg * 8;
      af[m][0] = *(const bf16x8*)p;
      af[m][1] = *(const bf16x8*)(p + 32);
    }

    float sacc[4][4];
#pragma unroll
    for (int m = 0; m < 4; ++m)
#pragma unroll
      for (int r = 0; r < 4; ++r) sacc[m][r] = 0.f;

    stage(0, tile0);
    if (nt > 1) stage(1, tile0 + 1);

#pragma unroll 1
    for (int s = 0; s < nt; ++s) {
      if (s + 1 < nt) asm volatile("s_waitcnt vmcnt(4)" ::: "memory");
      else            asm volatile("s_waitcnt vmcnt(0)" ::: "memory");
      __builtin_amdgcn_s_barrier();
      if (s + 2 < nt) stage((s + 2) % 3, tile0 + s + 2);

      const int cur = s % 3;
      const int cb = (tile0 + s) * 128 + wcol;
      const int full = (cb + 63 < TSZ1);

#pragma unroll
      for (int nh = 0; nh < 2; ++nh) {
        bf16x8 bf[2][2];
#pragma unroll
        for (int nn = 0; nn < 2; ++nn) {
          int ccol = wcol + (nh * 2 + nn) * 16 + lr;
#pragma unroll
          for (int kh = 0; kh < 2; ++kh) {
            int L = ccol * 128 + kh * 64 + lg * 16;
            bf[nn][kh] = *(const bf16x8*)((const char*)lds + cur * 16384 +
                                          (L ^ ((ccol & 7) << 4)));
          }
        }
        f32x4 acc[4][2];
#pragma unroll
        for (int m = 0; m < 4; ++m)
#pragma unroll
          for (int nn = 0; nn < 2; ++nn) {
            f32x4 a = (f32x4){0.f, 0.f, 0.f, 0.f};
            a = __builtin_amdgcn_mfma_f32_16x16x32_bf16(af[m][0], bf[nn][0], a, 0, 0, 0);
            a = __builtin_amdgcn_mfma_f32_16x16x32_bf16(af[m][1], bf[nn][1], a, 0, 0, 0);
            acc[m][nn] = a;
          }
        if (full) {
#pragma unroll
          for (int m = 0; m < 4; ++m)
#pragma unroll
            for (int r = 0; r < 4; ++r)
              sacc[m][r] += EXP2(acc[m][0][r]) + EXP2(acc[m][1][r]);
        } else {
#pragma unroll
          for (int m = 0; m < 4; ++m)
#pragma unroll
            for (int r = 0; r < 4; ++r) {
              float t = 0.f;
#pragma unroll
              for (int nn = 0; nn < 2; ++nn)
                if (cb + (nh * 2 + nn) * 16 + lr < TSZ1) t += EXP2(acc[m][nn][r]);
              sacc[m][r] += t;
            }
        }
      }
    }

#pragma unroll
    for (int m = 0; m < 4; ++m)
#pragma unroll
      for (int r = 0; r < 4; ++r) {
        float s = sacc[m][r];
        s += __shfl_xor(s, 1); s += __shfl_xor(s, 2);
        s += __shfl_xor(s, 4); s += __shfl_xor(s, 8);
        if (lr == 0) atomicAdd(&s1[rowBase + m * 16 + lg * 4 + r], s);
      }
    return;
  }

  if (bid < NB_HD + NB_C1 + NB_C0) {
    // ---- cluster 0: hb[:, :256] @ w0^T (compacted rows), K=256 ----
    const int b0 = bid - NB_HD - NB_C1;
    const int cpx = NB_C0 >> 3;        // 108
    const int sid = (b0 & 7) * cpx + (b0 >> 3);
    const int rowBlk = sid & 31;
    const int colChunk = sid >> 5;     // [0,27)
    if (rowBlk * 128 >= n01[0]) return;          // compaction early-exit
    gemm_core(hb, PD0 + PD1, w0b, PD0, TSZ0, PD0, colChunk, colChunk + 1,
              rowBlk * 128, nullptr, s0, nullptr, 0, 0,
              lds, lds + 3 * 4096, idx0);
    return;
  }

  // ---- target logits: one wave per row, 4 waves x 8 rows per block ----
  {
    const int b2 = bid - NB_HD - NB_C1 - NB_C0;   // [0,128)
    int lane = threadIdx.x & 63;
#pragma unroll 1
    for (int it = 0; it < 8; ++it) {
      int row = b2 * 32 + (int)(threadIdx.x >> 6) * 8 + it;
      int yv = y[row];
      int th = yv < CC0 ? yv : (yv < CC1 ? CC0 : CC0 + 1);

      const unsigned short* xr = xb + (size_t)row * NHID + lane * 16;
      const unsigned short* wr = hwb + (size_t)th * NHID + lane * 16;
      uint4 xa = *(const uint4*)xr,       wa = *(const uint4*)wr;
      uint4 xc = *(const uint4*)(xr + 8), wc = *(const uint4*)(wr + 8);
      float s = 0.f;
      uint32_t xs[8] = {xa.x, xa.y, xa.z, xa.w, xc.x, xc.y, xc.z, xc.w};
      uint32_t ws[8] = {wa.x, wa.y, wa.z, wa.w, wc.x, wc.y, wc.z, wc.w};
#pragma unroll
      for (int j = 0; j < 8; ++j)
        s += bfl(xs[j]) * bfl(ws[j]) + bfh(xs[j]) * bfh(ws[j]);
#pragma unroll
      for (int d = 1; d < 64; d <<= 1) s += __shfl_xor(s, d);

      float cl = 0.f;
      if (yv >= CC0) {
        if (yv < CC1) {
          int rel = yv - CC0;
          const unsigned short* hr = hb + (size_t)row * (PD0 + PD1) + lane * 4;
          const unsigned short* w0r = w0b + (size_t)rel * PD0 + lane * 4;
          uint2 ha = *(const uint2*)hr, wa0 = *(const uint2*)w0r;
          cl = bfl(ha.x) * bfl(wa0.x) + bfh(ha.x) * bfh(wa0.x)
             + bfl(ha.y) * bfl(wa0.y) + bfh(ha.y) * bfh(wa0.y);
        } else {
          int rel = yv - CC1;
          cl = bf1(hb[(size_t)row * (PD0 + PD1) + PD0 + lane])
             * bf1(w1b[(size_t)rel * PD1 + lane]);
        }
#pragma unroll
        for (int d = 1; d < 64; d <<= 1) cl += __shfl_xor(cl, d);
      }
      if (lane == 0) { ht[row] = s * LN2 + head_b[th]; tc[row] = (yv < CC0) ? 0.f : cl; }
    }
  }
}

// Per-row loss + parallel mean reduction. out[NROWS] pre-zeroed.
// Cluster sums are at compacted positions: s0[pos0[n]], s1[pos1[n]].
__global__ void rowloss(const float* __restrict__ hs, const float* __restrict__ ht,
                        const float* __restrict__ s0, const float* __restrict__ s1,
                        const float* __restrict__ tc,
                        const int* __restrict__ pos0, const int* __restrict__ pos1,
                        const int* __restrict__ y, float* __restrict__ out) {
  int n = blockIdx.x * 256 + threadIdx.x;
  int yv = y[n];
  float o = ht[n] - __builtin_amdgcn_logf(hs[n]) * LN2;
  if (yv >= CC0) {
    float sv = (yv < CC1) ? s0[pos0[n]] : s1[pos1[n]];
    o += tc[n] * LN2 - __builtin_amdgcn_logf(sv) * LN2;
  }
  out[n] = o;
  float l = o;
#pragma unroll
  for (int d = 1; d < 64; d <<= 1) l += __shfl_xor(l, d);
  __shared__ float red[4];
  if ((threadIdx.x & 63) == 0) red[threadIdx.x >> 6] = l;
  __syncthreads();
  if (threadIdx.x == 0)
    atomicAdd(&out[NROWS], -(red[0] + red[1] + red[2] + red[3]) / (float)NROWS);
}

extern "C" void kernel_launch(void* const* d_in, const int* in_sizes, int n_in,
                              void* d_out, int out_size, void* d_ws, size_t ws_size,
                              hipStream_t stream) {
  const float* x      = (const float*)d_in[0];
  const int*   y      = (const int*)d_in[1];
  const float* head_w = (const float*)d_in[2];
  const float* head_b = (const float*)d_in[3];
  const float* proj0  = (const float*)d_in[4];
  const float* w0     = (const float*)d_in[5];
  const float* proj1  = (const float*)d_in[6];
  const float* w1     = (const float*)d_in[7];
  float* out = (float*)d_out;

  char* wp = (char*)d_ws;
  unsigned short* xb  = (unsigned short*)wp; wp += (size_t)NROWS * NHID * 2;
  unsigned short* hpb = (unsigned short*)wp; wp += (size_t)HPN * NHID * 2;
  unsigned short* w0b = (unsigned short*)wp; wp += (size_t)TSZ0 * PD0 * 2;
  unsigned short* w1b = (unsigned short*)wp; wp += (size_t)TSZ1 * PD1 * 2;
  unsigned short* hb  = (unsigned short*)wp; wp += (size_t)NROWS * (PD0 + PD1) * 2;
  float* hs = (float*)wp; wp += NROWS * 4;
  float* s0 = (float*)wp; wp += NROWS * 4;
  float* s1 = (float*)wp; wp += NROWS * 4;
  float* ht = (float*)wp; wp += NROWS * 4;
  float* tc = (float*)wp; wp += NROWS * 4;
  float* dm = (float*)wp; wp += NROWS * 4;   // dummy sum target for proj
  int* idx0 = (int*)wp; wp += NROWS * 4;
  int* pos0 = (int*)wp; wp += NROWS * 4;
  int* idx1 = (int*)wp; wp += NROWS * 4;
  int* pos1 = (int*)wp; wp += NROWS * 4;
  int* n01  = (int*)wp; wp += 8 * 4;

  hipMemsetAsync(hs, 0, 3 * NROWS * 4, stream);      // zero hs, s0, s1
  hipMemsetAsync(out + NROWS, 0, 4, stream);         // zero loss accumulator

  // conv of x, head_w, proj0, proj1 + row compaction (block 1024)
  conv_part<<<dim3(1025), 256, 0, stream>>>(
      x, head_w, proj0, proj1, xb, y, idx0, pos0, idx1, pos1, n01);

  // fused mid: proj + w0/w1 conversion (short; only proj blocks on crit path)
  fused_mid<<<dim3(NB_MID), 256, 0, stream>>>(
      xb, hpb, hb, dm, w0, w1, xb);

  // fused tail: head-sum + c1 + c0 (compacted) + target gather, one dispatch
  fused_tail<<<dim3(NB_TAIL), 256, 0, stream>>>(
      hb, w0b, w1b, xb, hpb, head_b, y, idx0, idx1, n01, hs, s0, s1, ht, tc);

  // per-row loss + mean (out[NROWS] pre-zeroed)
  rowloss<<<dim3(NROWS / 256), 256, 0, stream>>>(
      hs, ht, s0, s1, tc, pos0, pos1, y, out);
}

// Round 17
// 102.927 us; speedup vs baseline: 1.0538x; 1.0538x over previous
//
#include <hip/hip_runtime.h>
#include <stdint.h>

#define NROWS 4096
#define NHID 1024
#define CC0 1675
#define CC1 5025
#define HEADSZ 1677
#define PD0 256
#define PD1 64
#define TSZ0 3350
#define TSZ1 45232
#define HPN (HEADSZ + PD0 + PD1)   // 1997: head + proj0 + proj1 fused B
#define TPC1 6
#define L2E 1.4426950408889634f
#define LN2 0.6931471805599453f

// fused_mid grid segmentation (segment starts divisible by 8)
#define NB_HD 448        // 14 colChunks x 32 rowBlks (head-sum, N=1677)
#define NB_PJ 96         // 3 colChunks x 32 rowBlks (proj, N=320)
#define NB_CW 512        // w0/w1 bf16 conversion (grid-stride)
#define NB_MID (NB_HD + NB_PJ + NB_CW)

// fused_tail grid segmentation (round-15 proven: 44.7us)
#define NB_C1 1888       // 59 colChunks(tpc=6) x 32 rowBlks
#define NB_C0 864        // 27 colChunks x 32 rowBlks (compaction early-exit)
#define NB_TG 1024       // 4096 rows / 4 per block
#define NB_TAIL (NB_C1 + NB_C0 + NB_TG)

typedef __attribute__((ext_vector_type(8))) __bf16 bf16x8;
typedef __attribute__((ext_vector_type(4))) float f32x4;

__device__ __forceinline__ unsigned short f2bf(float f) {
  union { float f; uint32_t u; } v; v.f = f;
  return (unsigned short)((v.u + 0x7FFFu + ((v.u >> 16) & 1u)) >> 16);
}
__device__ __forceinline__ float bfl(uint32_t u) {
  union { uint32_t u; float f; } v; v.u = u << 16; return v.f;
}
__device__ __forceinline__ float bfh(uint32_t u) {
  union { uint32_t u; float f; } v; v.u = u & 0xFFFF0000u; return v.f;
}
__device__ __forceinline__ float bf1(unsigned short u) {
  union { uint32_t u; float f; } v; v.u = ((uint32_t)u) << 16; return v.f;
}
#define EXP2(x) __builtin_amdgcn_exp2f(x)

// ---- conversion ranges (float4 units, compile-time) ----
#define CV1 1048576                  // x
#define CV2 1477888                  // head_w (xL2E)
#define CV3 1543424                  // proj0
#define CV4 1559808                  // proj1
#define CV5 1774208                  // w0 (xL2E)
#define CV6 2497920                  // w1 (xL2E)
#define CVW0 (CV5 - CV4)             // 214400
#define CVW  (CV6 - CV4)             // 938112

// conv for x, head_w, proj0, proj1 (blocks 0-1023) + row compaction
__global__ void conv_part(const float* __restrict__ x, const float* __restrict__ hw,
                          const float* __restrict__ p0, const float* __restrict__ p1,
                          unsigned short* __restrict__ dst,
                          const int* __restrict__ y,
                          int* __restrict__ idx0, int* __restrict__ pos0,
                          int* __restrict__ idx1, int* __restrict__ pos1,
                          int* __restrict__ n01) {
  if (blockIdx.x == 1024) {
    __shared__ int sc0[256], sc1[256], nsh[2];
    int t = threadIdx.x;
    int yl[16];
    int c0 = 0, c1 = 0;
#pragma unroll
    for (int k = 0; k < 16; ++k) {
      int yv = y[t * 16 + k];
      yl[k] = yv;
      c0 += (yv >= CC0 && yv < CC1);
      c1 += (yv >= CC1);
    }
    sc0[t] = c0; sc1[t] = c1;
    __syncthreads();
    if (t == 0) {
      int a0 = 0, a1 = 0;
      for (int i = 0; i < 256; ++i) {
        int v0 = sc0[i]; sc0[i] = a0; a0 += v0;
        int v1 = sc1[i]; sc1[i] = a1; a1 += v1;
      }
      n01[0] = a0; n01[1] = a1; nsh[0] = a0; nsh[1] = a1;
    }
    __syncthreads();
    int p0c = sc0[t], p1c = sc1[t];
#pragma unroll
    for (int k = 0; k < 16; ++k) {
      int n = t * 16 + k, yv = yl[k];
      if (yv >= CC0 && yv < CC1) { idx0[p0c] = n; pos0[n] = p0c; ++p0c; }
      else if (yv >= CC1)        { idx1[p1c] = n; pos1[n] = p1c; ++p1c; }
    }
    for (int j = nsh[0] + t; j < NROWS; j += 256) idx0[j] = 0;
    for (int j = nsh[1] + t; j < NROWS; j += 256) idx1[j] = 0;
    return;
  }
  const int stride = 1024 * 256;
  for (int i = blockIdx.x * 256 + threadIdx.x; i < CV4; i += stride) {
    const float* src; int off; float sc;
    if (i < CV1)      { src = x;  off = i;       sc = 1.f; }
    else if (i < CV2) { src = hw; off = i - CV1; sc = L2E; }
    else if (i < CV3) { src = p0; off = i - CV2; sc = 1.f; }
    else              { src = p1; off = i - CV3; sc = 1.f; }
    float4 v = reinterpret_cast<const float4*>(src)[off];
    ushort4 o;
    o.x = f2bf(v.x * sc); o.y = f2bf(v.y * sc);
    o.z = f2bf(v.z * sc); o.w = f2bf(v.w * sc);
    reinterpret_cast<ushort4*>(dst)[i] = o;
  }
}

#define GLOAD(g, l) __builtin_amdgcn_global_load_lds( \
    (const __attribute__((address_space(1))) uint32_t*)(const void*)(g), \
    (__attribute__((address_space(3))) uint32_t*)(void*)(l), 16, 0, 0)

// Involution swizzle on byte offsets within an 8KB [128][32]-bf16 tile:
// XOR bits 4-6 with bits 7-9. Bank-verified (round 2): conflicts 0.
#define SWZB(L) ((L) ^ ((((L) >> 7) & 7) << 4))

// --------------- 256-thread GEMM core (3-buffer counted ring) --------------
// Used by tail c0. gidx: optional A-row gather; nullptr = identity.
__device__ __forceinline__
void gemm_core(const unsigned short* __restrict__ A, int lda,
               const unsigned short* __restrict__ B, int ldb,
               int N, int K, int tile0, int tile1, int brow,
               const float* __restrict__ bias,
               float* __restrict__ sum_out,
               unsigned short* __restrict__ Cout, int ldc, int coutStart,
               unsigned short* AsB, unsigned short* BsB,
               const int* __restrict__ gidx) {
  const int tid = threadIdx.x;
  const int lane = tid & 63;
  const int wid = tid >> 6;
  const int wrow = (wid >> 1) * 64;
  const int wcol = (wid & 1) * 64;
  const int lr = lane & 15, lg = lane >> 4;
  const int nsteps = (tile1 - tile0) * (K >> 5);
  const int rowBase = brow + wrow;

  int arowc[2];
#pragma unroll
  for (int c = 0; c < 2; ++c) {
    int g = wid * 128 + c * 64 + lane;
    int S = SWZB(g * 16);
    int row = S >> 6;
    arowc[c] = gidx ? gidx[brow + row] : brow + row;
  }

  float sacc[4][4];
#pragma unroll
  for (int m = 0; m < 4; ++m)
#pragma unroll
    for (int r = 0; r < 4; ++r) sacc[m][r] = 0.f;

  auto stage = [&](int b, int tt, int kk) {
#pragma unroll
    for (int c = 0; c < 2; ++c) {
      int g = wid * 128 + c * 64 + lane;
      int L = g * 16;
      int S = SWZB(L);
      int row = S >> 6, ko = (S >> 4) & 3;
      GLOAD(A + (size_t)arowc[c] * lda + kk + ko * 8, (char*)AsB + b * 8192 + L);
      int bsrc = tt * 128 + row; bsrc = bsrc < N ? bsrc : N - 1;
      GLOAD(B + (size_t)bsrc * ldb + kk + ko * 8, (char*)BsB + b * 8192 + L);
    }
  };

  f32x4 acc[4][4];
#pragma unroll
  for (int m = 0; m < 4; ++m)
#pragma unroll
    for (int n = 0; n < 4; ++n) acc[m][n] = (f32x4){0.f, 0.f, 0.f, 0.f};

  int tp = tile0, kp = 0;
  auto adv = [&](int& t, int& k) { k += 32; if (k == K) { k = 0; ++t; } };
  stage(0, tp, kp); adv(tp, kp);
  if (nsteps > 1) { stage(1, tp, kp); adv(tp, kp); }

  int tile = tile0, k0 = 0;
  for (int s = 0; s < nsteps; ++s) {
    if (s + 1 < nsteps) asm volatile("s_waitcnt vmcnt(4)" ::: "memory");
    else                asm volatile("s_waitcnt vmcnt(0)" ::: "memory");
    __builtin_amdgcn_s_barrier();
    if (s + 2 < nsteps) { stage((s + 2) % 3, tp, kp); adv(tp, kp); }

    const int cur = s % 3;
    int k0n = k0 + 32, tn = tile;
    if (k0n == K) { k0n = 0; tn = tile + 1; }

    bf16x8 af[4], bfv[4];
#pragma unroll
    for (int m = 0; m < 4; ++m)
      af[m] = *(const bf16x8*)((const char*)AsB + cur * 8192 +
                               SWZB((wrow + m * 16 + lr) * 64 + lg * 16));
#pragma unroll
    for (int n = 0; n < 4; ++n)
      bfv[n] = *(const bf16x8*)((const char*)BsB + cur * 8192 +
                                SWZB((wcol + n * 16 + lr) * 64 + lg * 16));
#pragma unroll
    for (int m = 0; m < 4; ++m)
#pragma unroll
      for (int n = 0; n < 4; ++n)
        acc[m][n] = __builtin_amdgcn_mfma_f32_16x16x32_bf16(af[m], bfv[n], acc[m][n], 0, 0, 0);

    if (tn != tile) {
      const int cb = tile * 128 + wcol;
#pragma unroll
      for (int m = 0; m < 4; ++m)
#pragma unroll
        for (int n = 0; n < 4; ++n) {
#pragma unroll
          for (int r = 0; r < 4; ++r) {
            int col = cb + n * 16 + lr;
            if (col < N) {
              float v = acc[m][n][r];
              if (Cout && col >= coutStart) {
                int row = rowBase + m * 16 + lg * 4 + r;
                Cout[(size_t)row * ldc + (col - coutStart)] = f2bf(v);
              } else {
                if (bias) v = fmaf(bias[col], L2E, v);
                sacc[m][r] += EXP2(v);
              }
            }
          }
          acc[m][n] = (f32x4){0.f, 0.f, 0.f, 0.f};
        }
    }
    tile = tn; k0 = k0n;
  }

#pragma unroll
  for (int m = 0; m < 4; ++m)
#pragma unroll
    for (int r = 0; r < 4; ++r) {
      float s = sacc[m][r];
      s += __shfl_xor(s, 1); s += __shfl_xor(s, 2);
      s += __shfl_xor(s, 4); s += __shfl_xor(s, 8);
      if (lr == 0) atomicAdd(&sum_out[rowBase + m * 16 + lg * 4 + r], s);
    }
}

// ------- BK=64 2-buffer GEMM core (T3-minimum 2-phase; head/proj) ----------
// One 128-col tile, K in 64-wide steps (K/64 steps vs K/32): halves the
// barrier count. Per step: issue stage(s+1) (8 GLOADs) BEFORE compute(s);
// vmcnt(0)+barrier at step end. Buffers: 2 x (16KB A + 16KB B) = 64KB LDS.
// Each 16KB buffer = two 8KB k-half subtiles, each with the verified SWZB.
__device__ __forceinline__
void gemm_core2(const unsigned short* __restrict__ A, int lda,
                const unsigned short* __restrict__ B, int ldb,
                int N, int K, int tile0, int brow,
                const float* __restrict__ bias,
                float* __restrict__ sum_out,
                unsigned short* __restrict__ Cout, int ldc, int coutStart,
                char* AsB, char* BsB) {
  const int tid = threadIdx.x;
  const int lane = tid & 63;
  const int wid = tid >> 6;
  const int wrow = (wid >> 1) * 64;
  const int wcol = (wid & 1) * 64;
  const int lr = lane & 15, lg = lane >> 4;
  const int nsteps = K >> 6;
  const int rowBase = brow + wrow;

  auto stage = [&](int b, int kk) {
#pragma unroll
    for (int c = 0; c < 4; ++c) {
      int L = (c * 256 + tid) * 16;        // [0,16384)
      int kh = L >> 13;                    // k-half subtile
      int L8 = L & 8191;
      int S = SWZB(L8);
      int row = S >> 6, ko = (S >> 4) & 3;
      int koff = kk + kh * 32 + ko * 8;
      GLOAD(A + (size_t)(brow + row) * lda + koff, AsB + b * 16384 + L);
      int bsrc = tile0 * 128 + row; bsrc = bsrc < N ? bsrc : N - 1;
      GLOAD(B + (size_t)bsrc * ldb + koff, BsB + b * 16384 + L);
    }
  };

  f32x4 acc[4][4];
#pragma unroll
  for (int m = 0; m < 4; ++m)
#pragma unroll
    for (int n = 0; n < 4; ++n) acc[m][n] = (f32x4){0.f, 0.f, 0.f, 0.f};

  stage(0, 0);
  asm volatile("s_waitcnt vmcnt(0)" ::: "memory");
  __builtin_amdgcn_s_barrier();

  for (int s = 0; s < nsteps; ++s) {
    if (s + 1 < nsteps) stage((s + 1) & 1, (s + 1) * 64);  // in flight
    const int cur = s & 1;
#pragma unroll
    for (int kh = 0; kh < 2; ++kh) {
      bf16x8 af[4], bfv[4];
#pragma unroll
      for (int m = 0; m < 4; ++m)
        af[m] = *(const bf16x8*)(AsB + cur * 16384 + kh * 8192 +
                                 SWZB((wrow + m * 16 + lr) * 64 + lg * 16));
#pragma unroll
      for (int n = 0; n < 4; ++n)
        bfv[n] = *(const bf16x8*)(BsB + cur * 16384 + kh * 8192 +
                                  SWZB((wcol + n * 16 + lr) * 64 + lg * 16));
#pragma unroll
      for (int m = 0; m < 4; ++m)
#pragma unroll
        for (int n = 0; n < 4; ++n)
          acc[m][n] = __builtin_amdgcn_mfma_f32_16x16x32_bf16(af[m], bfv[n], acc[m][n], 0, 0, 0);
    }
    if (s + 1 < nsteps) {
      asm volatile("s_waitcnt vmcnt(0)" ::: "memory");  // stage(s+1) landed
      __builtin_amdgcn_s_barrier();
    }
  }

  // epilogue (single tile)
  const int cb = tile0 * 128 + wcol;
  float sacc[4][4];
#pragma unroll
  for (int m = 0; m < 4; ++m)
#pragma unroll
    for (int r = 0; r < 4; ++r) sacc[m][r] = 0.f;
#pragma unroll
  for (int m = 0; m < 4; ++m)
#pragma unroll
    for (int n = 0; n < 4; ++n)
#pragma unroll
      for (int r = 0; r < 4; ++r) {
        int col = cb + n * 16 + lr;
        if (col < N) {
          float v = acc[m][n][r];
          if (Cout && col >= coutStart) {
            int row = rowBase + m * 16 + lg * 4 + r;
            Cout[(size_t)row * ldc + (col - coutStart)] = f2bf(v);
          } else {
            if (bias) v = fmaf(bias[col], L2E, v);
            sacc[m][r] += EXP2(v);
          }
        }
      }
  if (sum_out) {
#pragma unroll
    for (int m = 0; m < 4; ++m)
#pragma unroll
      for (int r = 0; r < 4; ++r) {
        float s = sacc[m][r];
        s += __shfl_xor(s, 1); s += __shfl_xor(s, 2);
        s += __shfl_xor(s, 4); s += __shfl_xor(s, 8);
        if (lr == 0) atomicAdd(&sum_out[rowBase + m * 16 + lg * 4 + r], s);
      }
  }
}

// ---- fused mid: head-sum | proj | w0/w1 conversion (BK=64 2-phase) --------
__global__ __launch_bounds__(256, 2)
void fused_mid(const unsigned short* __restrict__ xb,
               const unsigned short* __restrict__ hpb,
               const float* __restrict__ head_b,
               float* __restrict__ hs,
               unsigned short* __restrict__ hb,
               const float* __restrict__ w0f, const float* __restrict__ w1f,
               unsigned short* __restrict__ dstAll) {
  __shared__ __align__(16) char lds[65536];   // 2 x (16KB A + 16KB B)
  const int bid = blockIdx.x;

  if (bid < NB_HD) {
    // head exp2-sum: rowBlk-major XCD swizzle (A panels L2-local)
    const int xcd = bid & 7;
    const int local = bid >> 3;          // [0,56)
    const int rowBlk = xcd * 4 + local / 14;
    const int colChunk = local % 14;
    gemm_core2(xb, NHID, hpb, NHID, HEADSZ, NHID, colChunk, rowBlk * 128,
               head_b, hs, nullptr, 0, 0, lds, lds + 32768);
    return;
  }

  if (bid < NB_HD + NB_PJ) {
    // proj: hb = xb @ [proj0;proj1]^T, N=320, K=1024
    const int b1 = bid - NB_HD;
    const int cpx = NB_PJ >> 3;          // 12
    const int sid = (b1 & 7) * cpx + (b1 >> 3);
    const int rowBlk = sid & 31;
    const int colChunk = sid >> 5;       // [0,3)
    gemm_core2(xb, NHID, hpb + (size_t)HEADSZ * NHID, NHID, PD0 + PD1, NHID,
               colChunk, rowBlk * 128,
               nullptr, nullptr, hb, PD0 + PD1, 0, lds, lds + 32768);
    return;
  }

  // w0/w1 f32->bf16 conversion (xL2E), grid-stride
  {
    const int b2 = bid - NB_HD - NB_PJ;  // [0,512)
    const int stride = NB_CW * 256;
    for (int i = b2 * 256 + (int)threadIdx.x; i < CVW; i += stride) {
      const float* src; int off;
      if (i < CVW0) { src = w0f; off = i; }
      else          { src = w1f; off = i - CVW0; }
      float4 v = reinterpret_cast<const float4*>(src)[off];
      ushort4 o;
      o.x = f2bf(v.x * L2E); o.y = f2bf(v.y * L2E);
      o.z = f2bf(v.z * L2E); o.w = f2bf(v.w * L2E);
      reinterpret_cast<ushort4*>(dstAll)[CV4 + i] = o;
    }
  }
}

// -- fused tail: c1 (compacted) | c0 (compacted) | target gather ------------
// (byte-identical to round-15's measured 44.7us version)
__global__ __launch_bounds__(256, 3)
void fused_tail(const unsigned short* __restrict__ hb,
                const unsigned short* __restrict__ w0b,
                const unsigned short* __restrict__ w1b,
                const unsigned short* __restrict__ xb,
                const unsigned short* __restrict__ hwb,
                const float* __restrict__ head_b,
                const int* __restrict__ y,
                const int* __restrict__ idx0, const int* __restrict__ idx1,
                const int* __restrict__ n01,
                float* __restrict__ s0, float* __restrict__ s1,
                float* __restrict__ ht, float* __restrict__ tc) {
  __shared__ __align__(16) unsigned short lds[6 * 4096];   // 48KB union
  const int bid = blockIdx.x;

  if (bid < NB_C1) {
    // ---- cluster 1: hb[:,256:] @ w1^T (compacted rows), K=64 ----
    const int tid = threadIdx.x;
    const int lane = tid & 63;
    const int wid = tid >> 6;
    const int lr = lane & 15, lg = lane >> 4;
    const int cpx = NB_C1 >> 3;        // 236
    const int sid = (bid & 7) * cpx + (bid >> 3);
    const int rowBlk = sid & 31;
    const int colChunk = sid >> 5;     // [0,59)
    if (rowBlk * 128 >= n01[1]) return;          // compaction early-exit
    const int rowBase = rowBlk * 128 + (wid >> 1) * 64;
    const int wcol = (wid & 1) * 64;
    const int tile0 = colChunk * TPC1;

    int colOff[4], srcOff[4];
#pragma unroll
    for (int c = 0; c < 4; ++c) {
      int L = (c * 256 + tid) * 16;
      int S = L ^ (((L >> 7) & 7) << 4);
      colOff[c] = S >> 7;
      srcOff[c] = (S & 127) >> 1;
    }
    auto stage = [&](int b, int t) {
#pragma unroll
      for (int c = 0; c < 4; ++c) {
        int gc = t * 128 + colOff[c];
        gc = gc < TSZ1 ? gc : TSZ1 - 1;
        GLOAD(w1b + (size_t)gc * PD1 + srcOff[c],
              (char*)lds + b * 16384 + (c * 256 + tid) * 16);
      }
    };

    bf16x8 af[4][2];
#pragma unroll
    for (int m = 0; m < 4; ++m) {
      int ridx = idx1[rowBase + m * 16 + lr];    // gathered A row
      const unsigned short* p = hb + PD0 +
          (size_t)ridx * (PD0 + PD1) + lg * 8;
      af[m][0] = *(const bf16x8*)p;
      af[m][1] = *(const bf16x8*)(p + 32);
    }

    float sacc[4][4];
#pragma unroll
    for (int m = 0; m < 4; ++m)
#pragma unroll
      for (int r = 0; r < 4; ++r) sacc[m][r] = 0.f;

    stage(0, tile0);
    stage(1, tile0 + 1);

#pragma unroll 1
    for (int s = 0; s < TPC1; ++s) {
      if (s + 1 < TPC1) asm volatile("s_waitcnt vmcnt(4)" ::: "memory");
      else              asm volatile("s_waitcnt vmcnt(0)" ::: "memory");
      __builtin_amdgcn_s_barrier();
      if (s + 2 < TPC1) stage((s + 2) % 3, tile0 + s + 2);

      const int cur = s % 3;
      const int cb = (tile0 + s) * 128 + wcol;
      const int full = (cb + 63 < TSZ1);

#pragma unroll
      for (int nh = 0; nh < 2; ++nh) {
        bf16x8 bf[2][2];
#pragma unroll
        for (int nn = 0; nn < 2; ++nn) {
          int ccol = wcol + (nh * 2 + nn) * 16 + lr;
#pragma unroll
          for (int kh = 0; kh < 2; ++kh) {
            int L = ccol * 128 + kh * 64 + lg * 16;
            bf[nn][kh] = *(const bf16x8*)((const char*)lds + cur * 16384 +
                                          (L ^ ((ccol & 7) << 4)));
          }
        }
        f32x4 acc[4][2];
#pragma unroll
        for (int m = 0; m < 4; ++m)
#pragma unroll
          for (int nn = 0; nn < 2; ++nn) {
            f32x4 a = (f32x4){0.f, 0.f, 0.f, 0.f};
            a = __builtin_amdgcn_mfma_f32_16x16x32_bf16(af[m][0], bf[nn][0], a, 0, 0, 0);
            a = __builtin_amdgcn_mfma_f32_16x16x32_bf16(af[m][1], bf[nn][1], a, 0, 0, 0);
            acc[m][nn] = a;
          }
        if (full) {
#pragma unroll
          for (int m = 0; m < 4; ++m)
#pragma unroll
            for (int r = 0; r < 4; ++r)
              sacc[m][r] += EXP2(acc[m][0][r]) + EXP2(acc[m][1][r]);
        } else {
#pragma unroll
          for (int m = 0; m < 4; ++m)
#pragma unroll
            for (int r = 0; r < 4; ++r) {
              float t = 0.f;
#pragma unroll
              for (int nn = 0; nn < 2; ++nn)
                if (cb + (nh * 2 + nn) * 16 + lr < TSZ1) t += EXP2(acc[m][nn][r]);
              sacc[m][r] += t;
            }
        }
      }
    }

#pragma unroll
    for (int m = 0; m < 4; ++m)
#pragma unroll
      for (int r = 0; r < 4; ++r) {
        float s = sacc[m][r];
        s += __shfl_xor(s, 1); s += __shfl_xor(s, 2);
        s += __shfl_xor(s, 4); s += __shfl_xor(s, 8);
        if (lr == 0) atomicAdd(&s1[rowBase + m * 16 + lg * 4 + r], s);
      }
    return;
  }

  if (bid < NB_C1 + NB_C0) {
    // ---- cluster 0: hb[:, :256] @ w0^T (compacted rows), K=256 ----
    const int b0 = bid - NB_C1;
    const int cpx = NB_C0 >> 3;        // 108
    const int sid = (b0 & 7) * cpx + (b0 >> 3);
    const int rowBlk = sid & 31;
    const int colChunk = sid >> 5;     // [0,27)
    if (rowBlk * 128 >= n01[0]) return;          // compaction early-exit
    gemm_core(hb, PD0 + PD1, w0b, PD0, TSZ0, PD0, colChunk, colChunk + 1,
              rowBlk * 128, nullptr, s0, nullptr, 0, 0,
              (unsigned short*)lds, (unsigned short*)lds + 3 * 4096, idx0);
    return;
  }

  // ---- target logits: one wave per row, 4 rows per block ----
  {
    const int b2 = bid - NB_C1 - NB_C0;
    int row = b2 * 4 + (threadIdx.x >> 6);
    int lane = threadIdx.x & 63;
    int yv = y[row];
    int th = yv < CC0 ? yv : (yv < CC1 ? CC0 : CC0 + 1);

    const unsigned short* xr = xb + (size_t)row * NHID + lane * 16;
    const unsigned short* wr = hwb + (size_t)th * NHID + lane * 16;
    uint4 xa = *(const uint4*)xr,       wa = *(const uint4*)wr;
    uint4 xc = *(const uint4*)(xr + 8), wc = *(const uint4*)(wr + 8);
    float s = 0.f;
    uint32_t xs[8] = {xa.x, xa.y, xa.z, xa.w, xc.x, xc.y, xc.z, xc.w};
    uint32_t ws[8] = {wa.x, wa.y, wa.z, wa.w, wc.x, wc.y, wc.z, wc.w};
#pragma unroll
    for (int j = 0; j < 8; ++j)
      s += bfl(xs[j]) * bfl(ws[j]) + bfh(xs[j]) * bfh(ws[j]);
#pragma unroll
    for (int d = 1; d < 64; d <<= 1) s += __shfl_xor(s, d);

    float cl = 0.f;
    if (yv >= CC0) {
      if (yv < CC1) {
        int rel = yv - CC0;
        const unsigned short* hr = hb + (size_t)row * (PD0 + PD1) + lane * 4;
        const unsigned short* w0r = w0b + (size_t)rel * PD0 + lane * 4;
        uint2 ha = *(const uint2*)hr, wa0 = *(const uint2*)w0r;
        cl = bfl(ha.x) * bfl(wa0.x) + bfh(ha.x) * bfh(wa0.x)
           + bfl(ha.y) * bfl(wa0.y) + bfh(ha.y) * bfh(wa0.y);
      } else {
        int rel = yv - CC1;
        cl = bf1(hb[(size_t)row * (PD0 + PD1) + PD0 + lane])
           * bf1(w1b[(size_t)rel * PD1 + lane]);
      }
#pragma unroll
      for (int d = 1; d < 64; d <<= 1) cl += __shfl_xor(cl, d);
    }
    if (lane == 0) { ht[row] = s * LN2 + head_b[th]; tc[row] = (yv < CC0) ? 0.f : cl; }
  }
}

// Per-row loss + parallel mean reduction. out[NROWS] pre-zeroed.
__global__ void rowloss(const float* __restrict__ hs, const float* __restrict__ ht,
                        const float* __restrict__ s0, const float* __restrict__ s1,
                        const float* __restrict__ tc,
                        const int* __restrict__ pos0, const int* __restrict__ pos1,
                        const int* __restrict__ y, float* __restrict__ out) {
  int n = blockIdx.x * 256 + threadIdx.x;
  int yv = y[n];
  float o = ht[n] - __builtin_amdgcn_logf(hs[n]) * LN2;
  if (yv >= CC0) {
    float sv = (yv < CC1) ? s0[pos0[n]] : s1[pos1[n]];
    o += tc[n] * LN2 - __builtin_amdgcn_logf(sv) * LN2;
  }
  out[n] = o;
  float l = o;
#pragma unroll
  for (int d = 1; d < 64; d <<= 1) l += __shfl_xor(l, d);
  __shared__ float red[4];
  if ((threadIdx.x & 63) == 0) red[threadIdx.x >> 6] = l;
  __syncthreads();
  if (threadIdx.x == 0)
    atomicAdd(&out[NROWS], -(red[0] + red[1] + red[2] + red[3]) / (float)NROWS);
}

extern "C" void kernel_launch(void* const* d_in, const int* in_sizes, int n_in,
                              void* d_out, int out_size, void* d_ws, size_t ws_size,
                              hipStream_t stream) {
  const float* x      = (const float*)d_in[0];
  const int*   y      = (const int*)d_in[1];
  const float* head_w = (const float*)d_in[2];
  const float* head_b = (const float*)d_in[3];
  const float* proj0  = (const float*)d_in[4];
  const float* w0     = (const float*)d_in[5];
  const float* proj1  = (const float*)d_in[6];
  const float* w1     = (const float*)d_in[7];
  float* out = (float*)d_out;

  char* wp = (char*)d_ws;
  unsigned short* xb  = (unsigned short*)wp; wp += (size_t)NROWS * NHID * 2;
  unsigned short* hpb = (unsigned short*)wp; wp += (size_t)HPN * NHID * 2;
  unsigned short* w0b = (unsigned short*)wp; wp += (size_t)TSZ0 * PD0 * 2;
  unsigned short* w1b = (unsigned short*)wp; wp += (size_t)TSZ1 * PD1 * 2;
  unsigned short* hb  = (unsigned short*)wp; wp += (size_t)NROWS * (PD0 + PD1) * 2;
  float* hs = (float*)wp; wp += NROWS * 4;
  float* s0 = (float*)wp; wp += NROWS * 4;
  float* s1 = (float*)wp; wp += NROWS * 4;
  float* ht = (float*)wp; wp += NROWS * 4;
  float* tc = (float*)wp; wp += NROWS * 4;
  int* idx0 = (int*)wp; wp += NROWS * 4;
  int* pos0 = (int*)wp; wp += NROWS * 4;
  int* idx1 = (int*)wp; wp += NROWS * 4;
  int* pos1 = (int*)wp; wp += NROWS * 4;
  int* n01  = (int*)wp; wp += 8 * 4;

  hipMemsetAsync(hs, 0, 3 * NROWS * 4, stream);      // zero hs, s0, s1
  hipMemsetAsync(out + NROWS, 0, 4, stream);         // zero loss accumulator

  // conv of x, head_w, proj0, proj1 + row compaction (block 1024)
  conv_part<<<dim3(1025), 256, 0, stream>>>(
      x, head_w, proj0, proj1, xb, y, idx0, pos0, idx1, pos1, n01);

  // fused mid: head-sum + proj (BK=64 2-phase) + w0/w1 conversion
  fused_mid<<<dim3(NB_MID), 256, 0, stream>>>(
      xb, hpb, head_b, hs, hb, w0, w1, xb);

  // fused tail: c1 + c0 (compacted) + target gather (round-15 proven)
  fused_tail<<<dim3(NB_TAIL), 256, 0, stream>>>(
      hb, w0b, w1b, xb, hpb, head_b, y, idx0, idx1, n01, s0, s1, ht, tc);

  // per-row loss + mean (out[NROWS] pre-zeroed)
  rowloss<<<dim3(NROWS / 256), 256, 0, stream>>>(
      hs, ht, s0, s1, tc, pos0, pos1, y, out);
}

// Round 18
// 97.793 us; speedup vs baseline: 1.1091x; 1.0525x over previous
//
#include <hip/hip_runtime.h>
#include <stdint.h>

#define NROWS 4096
#define NHID 1024
#define CC0 1675
#define CC1 5025
#define HEADSZ 1677
#define PD0 256
#define PD1 64
#define TSZ0 3350
#define TSZ1 45232
#define HPN (HEADSZ + PD0 + PD1)   // 1997: head + proj0 + proj1 fused B
#define TPC1 6
#define L2E 1.4426950408889634f
#define LN2 0.6931471805599453f

// fused_mid grid segmentation (segment starts divisible by 8)
#define NB_HD 896        // 14 colChunks x 64 rowBlks (64-row slim tiles)
#define NB_PJ 192        // 3 colChunks x 64 rowBlks (proj, N=320)
#define NB_CW 512        // w0/w1 bf16 conversion (grid-stride)
#define NB_MID (NB_HD + NB_PJ + NB_CW)

// fused_tail grid segmentation (round-15 proven: 44.7us)
#define NB_C1 1888       // 59 colChunks(tpc=6) x 32 rowBlks
#define NB_C0 864        // 27 colChunks x 32 rowBlks (compaction early-exit)
#define NB_TG 1024       // 4096 rows / 4 per block
#define NB_TAIL (NB_C1 + NB_C0 + NB_TG)

typedef __attribute__((ext_vector_type(8))) __bf16 bf16x8;
typedef __attribute__((ext_vector_type(4))) float f32x4;

__device__ __forceinline__ unsigned short f2bf(float f) {
  union { float f; uint32_t u; } v; v.f = f;
  return (unsigned short)((v.u + 0x7FFFu + ((v.u >> 16) & 1u)) >> 16);
}
__device__ __forceinline__ float bfl(uint32_t u) {
  union { uint32_t u; float f; } v; v.u = u << 16; return v.f;
}
__device__ __forceinline__ float bfh(uint32_t u) {
  union { uint32_t u; float f; } v; v.u = u & 0xFFFF0000u; return v.f;
}
__device__ __forceinline__ float bf1(unsigned short u) {
  union { uint32_t u; float f; } v; v.u = ((uint32_t)u) << 16; return v.f;
}
#define EXP2(x) __builtin_amdgcn_exp2f(x)

// ---- conversion ranges (float4 units, compile-time) ----
#define CV1 1048576                  // x
#define CV2 1477888                  // head_w (xL2E)
#define CV3 1543424                  // proj0
#define CV4 1559808                  // proj1
#define CV5 1774208                  // w0 (xL2E)
#define CV6 2497920                  // w1 (xL2E)
#define CVW0 (CV5 - CV4)             // 214400
#define CVW  (CV6 - CV4)             // 938112

// conv (blocks 0-1023) + row compaction (block 1024) + accumulator zeroing
// (blocks 1025-1031: hs/s0/s1 = 3*NROWS floats, contiguous; loss slot).
__global__ void conv_part(const float* __restrict__ x, const float* __restrict__ hw,
                          const float* __restrict__ p0, const float* __restrict__ p1,
                          unsigned short* __restrict__ dst,
                          const int* __restrict__ y,
                          int* __restrict__ idx0, int* __restrict__ pos0,
                          int* __restrict__ idx1, int* __restrict__ pos1,
                          int* __restrict__ n01,
                          float* __restrict__ hs3, float* __restrict__ outp) {
  if (blockIdx.x >= 1025) {
    int z = blockIdx.x - 1025;               // [0,7)
    for (int i = z * 256 + (int)threadIdx.x; i < 3 * NROWS; i += 7 * 256)
      hs3[i] = 0.f;
    if (z == 0 && threadIdx.x == 0) outp[NROWS] = 0.f;
    return;
  }
  if (blockIdx.x == 1024) {
    __shared__ int sc0[256], sc1[256], nsh[2];
    int t = threadIdx.x;
    int yl[16];
    int c0 = 0, c1 = 0;
#pragma unroll
    for (int k = 0; k < 16; ++k) {
      int yv = y[t * 16 + k];
      yl[k] = yv;
      c0 += (yv >= CC0 && yv < CC1);
      c1 += (yv >= CC1);
    }
    sc0[t] = c0; sc1[t] = c1;
    __syncthreads();
    if (t == 0) {
      int a0 = 0, a1 = 0;
      for (int i = 0; i < 256; ++i) {
        int v0 = sc0[i]; sc0[i] = a0; a0 += v0;
        int v1 = sc1[i]; sc1[i] = a1; a1 += v1;
      }
      n01[0] = a0; n01[1] = a1; nsh[0] = a0; nsh[1] = a1;
    }
    __syncthreads();
    int p0c = sc0[t], p1c = sc1[t];
#pragma unroll
    for (int k = 0; k < 16; ++k) {
      int n = t * 16 + k, yv = yl[k];
      if (yv >= CC0 && yv < CC1) { idx0[p0c] = n; pos0[n] = p0c; ++p0c; }
      else if (yv >= CC1)        { idx1[p1c] = n; pos1[n] = p1c; ++p1c; }
    }
    for (int j = nsh[0] + t; j < NROWS; j += 256) idx0[j] = 0;
    for (int j = nsh[1] + t; j < NROWS; j += 256) idx1[j] = 0;
    return;
  }
  const int stride = 1024 * 256;
  for (int i = blockIdx.x * 256 + threadIdx.x; i < CV4; i += stride) {
    const float* src; int off; float sc;
    if (i < CV1)      { src = x;  off = i;       sc = 1.f; }
    else if (i < CV2) { src = hw; off = i - CV1; sc = L2E; }
    else if (i < CV3) { src = p0; off = i - CV2; sc = 1.f; }
    else              { src = p1; off = i - CV3; sc = 1.f; }
    float4 v = reinterpret_cast<const float4*>(src)[off];
    ushort4 o;
    o.x = f2bf(v.x * sc); o.y = f2bf(v.y * sc);
    o.z = f2bf(v.z * sc); o.w = f2bf(v.w * sc);
    reinterpret_cast<ushort4*>(dst)[i] = o;
  }
}

#define GLOAD(g, l) __builtin_amdgcn_global_load_lds( \
    (const __attribute__((address_space(1))) uint32_t*)(const void*)(g), \
    (__attribute__((address_space(3))) uint32_t*)(void*)(l), 16, 0, 0)

// Involution swizzle on byte offsets: XOR bits 4-6 with bits 7-9.
// Bank-verified (round 2): conflicts 0. Valid within 4KB/8KB subtiles.
#define SWZB(L) ((L) ^ ((((L) >> 7) & 7) << 4))

// --------------- 256-thread GEMM core (3-buffer counted ring) --------------
// Used by tail c0. gidx: optional A-row gather; nullptr = identity.
__device__ __forceinline__
void gemm_core(const unsigned short* __restrict__ A, int lda,
               const unsigned short* __restrict__ B, int ldb,
               int N, int K, int tile0, int tile1, int brow,
               const float* __restrict__ bias,
               float* __restrict__ sum_out,
               unsigned short* __restrict__ Cout, int ldc, int coutStart,
               unsigned short* AsB, unsigned short* BsB,
               const int* __restrict__ gidx) {
  const int tid = threadIdx.x;
  const int lane = tid & 63;
  const int wid = tid >> 6;
  const int wrow = (wid >> 1) * 64;
  const int wcol = (wid & 1) * 64;
  const int lr = lane & 15, lg = lane >> 4;
  const int nsteps = (tile1 - tile0) * (K >> 5);
  const int rowBase = brow + wrow;

  int arowc[2];
#pragma unroll
  for (int c = 0; c < 2; ++c) {
    int g = wid * 128 + c * 64 + lane;
    int S = SWZB(g * 16);
    int row = S >> 6;
    arowc[c] = gidx ? gidx[brow + row] : brow + row;
  }

  float sacc[4][4];
#pragma unroll
  for (int m = 0; m < 4; ++m)
#pragma unroll
    for (int r = 0; r < 4; ++r) sacc[m][r] = 0.f;

  auto stage = [&](int b, int tt, int kk) {
#pragma unroll
    for (int c = 0; c < 2; ++c) {
      int g = wid * 128 + c * 64 + lane;
      int L = g * 16;
      int S = SWZB(L);
      int row = S >> 6, ko = (S >> 4) & 3;
      GLOAD(A + (size_t)arowc[c] * lda + kk + ko * 8, (char*)AsB + b * 8192 + L);
      int bsrc = tt * 128 + row; bsrc = bsrc < N ? bsrc : N - 1;
      GLOAD(B + (size_t)bsrc * ldb + kk + ko * 8, (char*)BsB + b * 8192 + L);
    }
  };

  f32x4 acc[4][4];
#pragma unroll
  for (int m = 0; m < 4; ++m)
#pragma unroll
    for (int n = 0; n < 4; ++n) acc[m][n] = (f32x4){0.f, 0.f, 0.f, 0.f};

  int tp = tile0, kp = 0;
  auto adv = [&](int& t, int& k) { k += 32; if (k == K) { k = 0; ++t; } };
  stage(0, tp, kp); adv(tp, kp);
  if (nsteps > 1) { stage(1, tp, kp); adv(tp, kp); }

  int tile = tile0, k0 = 0;
  for (int s = 0; s < nsteps; ++s) {
    if (s + 1 < nsteps) asm volatile("s_waitcnt vmcnt(4)" ::: "memory");
    else                asm volatile("s_waitcnt vmcnt(0)" ::: "memory");
    __builtin_amdgcn_s_barrier();
    if (s + 2 < nsteps) { stage((s + 2) % 3, tp, kp); adv(tp, kp); }

    const int cur = s % 3;
    int k0n = k0 + 32, tn = tile;
    if (k0n == K) { k0n = 0; tn = tile + 1; }

    bf16x8 af[4], bfv[4];
#pragma unroll
    for (int m = 0; m < 4; ++m)
      af[m] = *(const bf16x8*)((const char*)AsB + cur * 8192 +
                               SWZB((wrow + m * 16 + lr) * 64 + lg * 16));
#pragma unroll
    for (int n = 0; n < 4; ++n)
      bfv[n] = *(const bf16x8*)((const char*)BsB + cur * 8192 +
                                SWZB((wcol + n * 16 + lr) * 64 + lg * 16));
#pragma unroll
    for (int m = 0; m < 4; ++m)
#pragma unroll
      for (int n = 0; n < 4; ++n)
        acc[m][n] = __builtin_amdgcn_mfma_f32_16x16x32_bf16(af[m], bfv[n], acc[m][n], 0, 0, 0);

    if (tn != tile) {
      const int cb = tile * 128 + wcol;
#pragma unroll
      for (int m = 0; m < 4; ++m)
#pragma unroll
        for (int n = 0; n < 4; ++n) {
#pragma unroll
          for (int r = 0; r < 4; ++r) {
            int col = cb + n * 16 + lr;
            if (col < N) {
              float v = acc[m][n][r];
              if (Cout && col >= coutStart) {
                int row = rowBase + m * 16 + lg * 4 + r;
                Cout[(size_t)row * ldc + (col - coutStart)] = f2bf(v);
              } else {
                if (bias) v = fmaf(bias[col], L2E, v);
                sacc[m][r] += EXP2(v);
              }
            }
          }
          acc[m][n] = (f32x4){0.f, 0.f, 0.f, 0.f};
        }
    }
    tile = tn; k0 = k0n;
  }

#pragma unroll
  for (int m = 0; m < 4; ++m)
#pragma unroll
    for (int r = 0; r < 4; ++r) {
      float s = sacc[m][r];
      s += __shfl_xor(s, 1); s += __shfl_xor(s, 2);
      s += __shfl_xor(s, 4); s += __shfl_xor(s, 8);
      if (lr == 0) atomicAdd(&sum_out[rowBase + m * 16 + lg * 4 + r], s);
    }
}

// ---- slim GEMM core: 64 rows x 128 cols, BK=64, 2-buffer, 48KB LDS -------
// 4 waves each own 32x64 (acc[2][4] = 32 regs). Per step: 6 GLOADs/thread
// (A 8KB + B 16KB) issued BEFORE compute; vmcnt(0)+barrier at step end.
// AsB: 2 x 8KB (two 4KB k-half subtiles); BsB: 2 x 16KB (two 8KB halves).
__device__ __forceinline__
void gemm_core3(const unsigned short* __restrict__ A, int lda,
                const unsigned short* __restrict__ B, int ldb,
                int N, int K, int tile0, int brow,
                const float* __restrict__ bias,
                float* __restrict__ sum_out,
                unsigned short* __restrict__ Cout, int ldc,
                char* AsB, char* BsB) {
  const int tid = threadIdx.x;
  const int lane = tid & 63;
  const int wid = tid >> 6;
  const int wrow = (wid >> 1) * 32;    // 2 row halves of 32
  const int wcol = (wid & 1) * 64;     // 2 col halves of 64
  const int lr = lane & 15, lg = lane >> 4;
  const int nsteps = K >> 6;
  const int rowBase = brow + wrow;

  auto stage = [&](int b, int kk) {
#pragma unroll
    for (int kh = 0; kh < 2; ++kh) {
      // A k-half subtile: 4KB, 1 chunk/thread
      {
        int L4 = tid * 16;
        int S = SWZB(L4);
        int row = S >> 6, ko = (S >> 4) & 3;
        GLOAD(A + (size_t)(brow + row) * lda + kk + kh * 32 + ko * 8,
              AsB + b * 8192 + kh * 4096 + L4);
      }
      // B k-half subtile: 8KB, 2 chunks/thread
#pragma unroll
      for (int c = 0; c < 2; ++c) {
        int L8 = (c * 256 + tid) * 16;
        int S = SWZB(L8);
        int col = S >> 6, ko = (S >> 4) & 3;
        int bsrc = tile0 * 128 + col; bsrc = bsrc < N ? bsrc : N - 1;
        GLOAD(B + (size_t)bsrc * ldb + kk + kh * 32 + ko * 8,
              BsB + b * 16384 + kh * 8192 + L8);
      }
    }
  };

  f32x4 acc[2][4];
#pragma unroll
  for (int m = 0; m < 2; ++m)
#pragma unroll
    for (int n = 0; n < 4; ++n) acc[m][n] = (f32x4){0.f, 0.f, 0.f, 0.f};

  stage(0, 0);
  asm volatile("s_waitcnt vmcnt(0)" ::: "memory");
  __builtin_amdgcn_s_barrier();

  for (int s = 0; s < nsteps; ++s) {
    if (s + 1 < nsteps) stage((s + 1) & 1, (s + 1) * 64);  // in flight
    const int cur = s & 1;
#pragma unroll
    for (int kh = 0; kh < 2; ++kh) {
      bf16x8 af[2], bfv[4];
#pragma unroll
      for (int m = 0; m < 2; ++m)
        af[m] = *(const bf16x8*)(AsB + cur * 8192 + kh * 4096 +
                                 SWZB((wrow + m * 16 + lr) * 64 + lg * 16));
#pragma unroll
      for (int n = 0; n < 4; ++n)
        bfv[n] = *(const bf16x8*)(BsB + cur * 16384 + kh * 8192 +
                                  SWZB((wcol + n * 16 + lr) * 64 + lg * 16));
#pragma unroll
      for (int m = 0; m < 2; ++m)
#pragma unroll
        for (int n = 0; n < 4; ++n)
          acc[m][n] = __builtin_amdgcn_mfma_f32_16x16x32_bf16(af[m], bfv[n], acc[m][n], 0, 0, 0);
    }
    if (s + 1 < nsteps) {
      asm volatile("s_waitcnt vmcnt(0)" ::: "memory");
      __builtin_amdgcn_s_barrier();
    }
  }

  const int cb = tile0 * 128 + wcol;
  float sacc[2][4];
#pragma unroll
  for (int m = 0; m < 2; ++m)
#pragma unroll
    for (int r = 0; r < 4; ++r) sacc[m][r] = 0.f;
#pragma unroll
  for (int m = 0; m < 2; ++m)
#pragma unroll
    for (int n = 0; n < 4; ++n)
#pragma unroll
      for (int r = 0; r < 4; ++r) {
        int col = cb + n * 16 + lr;
        if (col < N) {
          float v = acc[m][n][r];
          if (Cout) {
            int row = rowBase + m * 16 + lg * 4 + r;
            Cout[(size_t)row * ldc + col] = f2bf(v);
          } else {
            if (bias) v = fmaf(bias[col], L2E, v);
            sacc[m][r] += EXP2(v);
          }
        }
      }
  if (sum_out) {
#pragma unroll
    for (int m = 0; m < 2; ++m)
#pragma unroll
      for (int r = 0; r < 4; ++r) {
        float s = sacc[m][r];
        s += __shfl_xor(s, 1); s += __shfl_xor(s, 2);
        s += __shfl_xor(s, 4); s += __shfl_xor(s, 8);
        if (lr == 0) atomicAdd(&sum_out[rowBase + m * 16 + lg * 4 + r], s);
      }
  }
}

// ---- fused mid: head-sum | proj (slim 64x128 BK64) | w0/w1 conversion -----
__global__ __launch_bounds__(256, 3)
void fused_mid(const unsigned short* __restrict__ xb,
               const unsigned short* __restrict__ hpb,
               const float* __restrict__ head_b,
               float* __restrict__ hs,
               unsigned short* __restrict__ hb,
               const float* __restrict__ w0f, const float* __restrict__ w1f,
               unsigned short* __restrict__ dstAll) {
  __shared__ __align__(16) char lds[49152];   // 16KB A(2x8) + 32KB B(2x16)
  const int bid = blockIdx.x;

  if (bid < NB_HD) {
    // head exp2-sum: rowBlk-major XCD swizzle (A panels L2-local)
    const int xcd = bid & 7;
    const int local = bid >> 3;          // [0,112)
    const int rowBlk = xcd * 8 + local / 14;   // [0,64)
    const int colChunk = local % 14;
    gemm_core3(xb, NHID, hpb, NHID, HEADSZ, NHID, colChunk, rowBlk * 64,
               head_b, hs, nullptr, 0, lds, lds + 16384);
    return;
  }

  if (bid < NB_HD + NB_PJ) {
    // proj: hb = xb @ [proj0;proj1]^T, N=320, K=1024
    const int b1 = bid - NB_HD;
    const int cpx = NB_PJ >> 3;          // 24
    const int sid = (b1 & 7) * cpx + (b1 >> 3);
    const int rowBlk = sid & 63;         // [0,64)
    const int colChunk = sid >> 6;       // [0,3)
    gemm_core3(xb, NHID, hpb + (size_t)HEADSZ * NHID, NHID, PD0 + PD1, NHID,
               colChunk, rowBlk * 64,
               nullptr, nullptr, hb, PD0 + PD1, lds, lds + 16384);
    return;
  }

  // w0/w1 f32->bf16 conversion (xL2E), grid-stride
  {
    const int b2 = bid - NB_HD - NB_PJ;  // [0,512)
    const int stride = NB_CW * 256;
    for (int i = b2 * 256 + (int)threadIdx.x; i < CVW; i += stride) {
      const float* src; int off;
      if (i < CVW0) { src = w0f; off = i; }
      else          { src = w1f; off = i - CVW0; }
      float4 v = reinterpret_cast<const float4*>(src)[off];
      ushort4 o;
      o.x = f2bf(v.x * L2E); o.y = f2bf(v.y * L2E);
      o.z = f2bf(v.z * L2E); o.w = f2bf(v.w * L2E);
      reinterpret_cast<ushort4*>(dstAll)[CV4 + i] = o;
    }
  }
}

// -- fused tail: c1 (compacted) | c0 (compacted) | target gather ------------
// (byte-identical to round-15's measured 44.7us version)
__global__ __launch_bounds__(256, 3)
void fused_tail(const unsigned short* __restrict__ hb,
                const unsigned short* __restrict__ w0b,
                const unsigned short* __restrict__ w1b,
                const unsigned short* __restrict__ xb,
                const unsigned short* __restrict__ hwb,
                const float* __restrict__ head_b,
                const int* __restrict__ y,
                const int* __restrict__ idx0, const int* __restrict__ idx1,
                const int* __restrict__ n01,
                float* __restrict__ s0, float* __restrict__ s1,
                float* __restrict__ ht, float* __restrict__ tc) {
  __shared__ __align__(16) unsigned short lds[6 * 4096];   // 48KB union
  const int bid = blockIdx.x;

  if (bid < NB_C1) {
    // ---- cluster 1: hb[:,256:] @ w1^T (compacted rows), K=64 ----
    const int tid = threadIdx.x;
    const int lane = tid & 63;
    const int wid = tid >> 6;
    const int lr = lane & 15, lg = lane >> 4;
    const int cpx = NB_C1 >> 3;        // 236
    const int sid = (bid & 7) * cpx + (bid >> 3);
    const int rowBlk = sid & 31;
    const int colChunk = sid >> 5;     // [0,59)
    if (rowBlk * 128 >= n01[1]) return;          // compaction early-exit
    const int rowBase = rowBlk * 128 + (wid >> 1) * 64;
    const int wcol = (wid & 1) * 64;
    const int tile0 = colChunk * TPC1;

    int colOff[4], srcOff[4];
#pragma unroll
    for (int c = 0; c < 4; ++c) {
      int L = (c * 256 + tid) * 16;
      int S = L ^ (((L >> 7) & 7) << 4);
      colOff[c] = S >> 7;
      srcOff[c] = (S & 127) >> 1;
    }
    auto stage = [&](int b, int t) {
#pragma unroll
      for (int c = 0; c < 4; ++c) {
        int gc = t * 128 + colOff[c];
        gc = gc < TSZ1 ? gc : TSZ1 - 1;
        GLOAD(w1b + (size_t)gc * PD1 + srcOff[c],
              (char*)lds + b * 16384 + (c * 256 + tid) * 16);
      }
    };

    bf16x8 af[4][2];
#pragma unroll
    for (int m = 0; m < 4; ++m) {
      int ridx = idx1[rowBase + m * 16 + lr];    // gathered A row
      const unsigned short* p = hb + PD0 +
          (size_t)ridx * (PD0 + PD1) + lg * 8;
      af[m][0] = *(const bf16x8*)p;
      af[m][1] = *(const bf16x8*)(p + 32);
    }

    float sacc[4][4];
#pragma unroll
    for (int m = 0; m < 4; ++m)
#pragma unroll
      for (int r = 0; r < 4; ++r) sacc[m][r] = 0.f;

    stage(0, tile0);
    stage(1, tile0 + 1);

#pragma unroll 1
    for (int s = 0; s < TPC1; ++s) {
      if (s + 1 < TPC1) asm volatile("s_waitcnt vmcnt(4)" ::: "memory");
      else              asm volatile("s_waitcnt vmcnt(0)" ::: "memory");
      __builtin_amdgcn_s_barrier();
      if (s + 2 < TPC1) stage((s + 2) % 3, tile0 + s + 2);

      const int cur = s % 3;
      const int cb = (tile0 + s) * 128 + wcol;
      const int full = (cb + 63 < TSZ1);

#pragma unroll
      for (int nh = 0; nh < 2; ++nh) {
        bf16x8 bf[2][2];
#pragma unroll
        for (int nn = 0; nn < 2; ++nn) {
          int ccol = wcol + (nh * 2 + nn) * 16 + lr;
#pragma unroll
          for (int kh = 0; kh < 2; ++kh) {
            int L = ccol * 128 + kh * 64 + lg * 16;
            bf[nn][kh] = *(const bf16x8*)((const char*)lds + cur * 16384 +
                                          (L ^ ((ccol & 7) << 4)));
          }
        }
        f32x4 acc[4][2];
#pragma unroll
        for (int m = 0; m < 4; ++m)
#pragma unroll
          for (int nn = 0; nn < 2; ++nn) {
            f32x4 a = (f32x4){0.f, 0.f, 0.f, 0.f};
            a = __builtin_amdgcn_mfma_f32_16x16x32_bf16(af[m][0], bf[nn][0], a, 0, 0, 0);
            a = __builtin_amdgcn_mfma_f32_16x16x32_bf16(af[m][1], bf[nn][1], a, 0, 0, 0);
            acc[m][nn] = a;
          }
        if (full) {
#pragma unroll
          for (int m = 0; m < 4; ++m)
#pragma unroll
            for (int r = 0; r < 4; ++r)
              sacc[m][r] += EXP2(acc[m][0][r]) + EXP2(acc[m][1][r]);
        } else {
#pragma unroll
          for (int m = 0; m < 4; ++m)
#pragma unroll
            for (int r = 0; r < 4; ++r) {
              float t = 0.f;
#pragma unroll
              for (int nn = 0; nn < 2; ++nn)
                if (cb + (nh * 2 + nn) * 16 + lr < TSZ1) t += EXP2(acc[m][nn][r]);
              sacc[m][r] += t;
            }
        }
      }
    }

#pragma unroll
    for (int m = 0; m < 4; ++m)
#pragma unroll
      for (int r = 0; r < 4; ++r) {
        float s = sacc[m][r];
        s += __shfl_xor(s, 1); s += __shfl_xor(s, 2);
        s += __shfl_xor(s, 4); s += __shfl_xor(s, 8);
        if (lr == 0) atomicAdd(&s1[rowBase + m * 16 + lg * 4 + r], s);
      }
    return;
  }

  if (bid < NB_C1 + NB_C0) {
    // ---- cluster 0: hb[:, :256] @ w0^T (compacted rows), K=256 ----
    const int b0 = bid - NB_C1;
    const int cpx = NB_C0 >> 3;        // 108
    const int sid = (b0 & 7) * cpx + (b0 >> 3);
    const int rowBlk = sid & 31;
    const int colChunk = sid >> 5;     // [0,27)
    if (rowBlk * 128 >= n01[0]) return;          // compaction early-exit
    gemm_core(hb, PD0 + PD1, w0b, PD0, TSZ0, PD0, colChunk, colChunk + 1,
              rowBlk * 128, nullptr, s0, nullptr, 0, 0,
              (unsigned short*)lds, (unsigned short*)lds + 3 * 4096, idx0);
    return;
  }

  // ---- target logits: one wave per row, 4 rows per block ----
  {
    const int b2 = bid - NB_C1 - NB_C0;
    int row = b2 * 4 + (threadIdx.x >> 6);
    int lane = threadIdx.x & 63;
    int yv = y[row];
    int th = yv < CC0 ? yv : (yv < CC1 ? CC0 : CC0 + 1);

    const unsigned short* xr = xb + (size_t)row * NHID + lane * 16;
    const unsigned short* wr = hwb + (size_t)th * NHID + lane * 16;
    uint4 xa = *(const uint4*)xr,       wa = *(const uint4*)wr;
    uint4 xc = *(const uint4*)(xr + 8), wc = *(const uint4*)(wr + 8);
    float s = 0.f;
    uint32_t xs[8] = {xa.x, xa.y, xa.z, xa.w, xc.x, xc.y, xc.z, xc.w};
    uint32_t ws[8] = {wa.x, wa.y, wa.z, wa.w, wc.x, wc.y, wc.z, wc.w};
#pragma unroll
    for (int j = 0; j < 8; ++j)
      s += bfl(xs[j]) * bfl(ws[j]) + bfh(xs[j]) * bfh(ws[j]);
#pragma unroll
    for (int d = 1; d < 64; d <<= 1) s += __shfl_xor(s, d);

    float cl = 0.f;
    if (yv >= CC0) {
      if (yv < CC1) {
        int rel = yv - CC0;
        const unsigned short* hr = hb + (size_t)row * (PD0 + PD1) + lane * 4;
        const unsigned short* w0r = w0b + (size_t)rel * PD0 + lane * 4;
        uint2 ha = *(const uint2*)hr, wa0 = *(const uint2*)w0r;
        cl = bfl(ha.x) * bfl(wa0.x) + bfh(ha.x) * bfh(wa0.x)
           + bfl(ha.y) * bfl(wa0.y) + bfh(ha.y) * bfh(wa0.y);
      } else {
        int rel = yv - CC1;
        cl = bf1(hb[(size_t)row * (PD0 + PD1) + PD0 + lane])
           * bf1(w1b[(size_t)rel * PD1 + lane]);
      }
#pragma unroll
      for (int d = 1; d < 64; d <<= 1) cl += __shfl_xor(cl, d);
    }
    if (lane == 0) { ht[row] = s * LN2 + head_b[th]; tc[row] = (yv < CC0) ? 0.f : cl; }
  }
}

// Per-row loss + parallel mean reduction. out[NROWS] pre-zeroed (conv_part).
__global__ void rowloss(const float* __restrict__ hs, const float* __restrict__ ht,
                        const float* __restrict__ s0, const float* __restrict__ s1,
                        const float* __restrict__ tc,
                        const int* __restrict__ pos0, const int* __restrict__ pos1,
                        const int* __restrict__ y, float* __restrict__ out) {
  int n = blockIdx.x * 256 + threadIdx.x;
  int yv = y[n];
  float o = ht[n] - __builtin_amdgcn_logf(hs[n]) * LN2;
  if (yv >= CC0) {
    float sv = (yv < CC1) ? s0[pos0[n]] : s1[pos1[n]];
    o += tc[n] * LN2 - __builtin_amdgcn_logf(sv) * LN2;
  }
  out[n] = o;
  float l = o;
#pragma unroll
  for (int d = 1; d < 64; d <<= 1) l += __shfl_xor(l, d);
  __shared__ float red[4];
  if ((threadIdx.x & 63) == 0) red[threadIdx.x >> 6] = l;
  __syncthreads();
  if (threadIdx.x == 0)
    atomicAdd(&out[NROWS], -(red[0] + red[1] + red[2] + red[3]) / (float)NROWS);
}

extern "C" void kernel_launch(void* const* d_in, const int* in_sizes, int n_in,
                              void* d_out, int out_size, void* d_ws, size_t ws_size,
                              hipStream_t stream) {
  const float* x      = (const float*)d_in[0];
  const int*   y      = (const int*)d_in[1];
  const float* head_w = (const float*)d_in[2];
  const float* head_b = (const float*)d_in[3];
  const float* proj0  = (const float*)d_in[4];
  const float* w0     = (const float*)d_in[5];
  const float* proj1  = (const float*)d_in[6];
  const float* w1     = (const float*)d_in[7];
  float* out = (float*)d_out;

  char* wp = (char*)d_ws;
  unsigned short* xb  = (unsigned short*)wp; wp += (size_t)NROWS * NHID * 2;
  unsigned short* hpb = (unsigned short*)wp; wp += (size_t)HPN * NHID * 2;
  unsigned short* w0b = (unsigned short*)wp; wp += (size_t)TSZ0 * PD0 * 2;
  unsigned short* w1b = (unsigned short*)wp; wp += (size_t)TSZ1 * PD1 * 2;
  unsigned short* hb  = (unsigned short*)wp; wp += (size_t)NROWS * (PD0 + PD1) * 2;
  float* hs = (float*)wp; wp += NROWS * 4;
  float* s0 = (float*)wp; wp += NROWS * 4;
  float* s1 = (float*)wp; wp += NROWS * 4;
  float* ht = (float*)wp; wp += NROWS * 4;
  float* tc = (float*)wp; wp += NROWS * 4;
  int* idx0 = (int*)wp; wp += NROWS * 4;
  int* pos0 = (int*)wp; wp += NROWS * 4;
  int* idx1 = (int*)wp; wp += NROWS * 4;
  int* pos1 = (int*)wp; wp += NROWS * 4;
  int* n01  = (int*)wp; wp += 8 * 4;

  // conv + compaction + accumulator zeroing (no separate memsets)
  conv_part<<<dim3(1032), 256, 0, stream>>>(
      x, head_w, proj0, proj1, xb, y, idx0, pos0, idx1, pos1, n01, hs, out);

  // fused mid: head-sum + proj (slim 64x128 BK64, 3/CU) + w0/w1 conversion
  fused_mid<<<dim3(NB_MID), 256, 0, stream>>>(
      xb, hpb, head_b, hs, hb, w0, w1, xb);

  // fused tail: c1 + c0 (compacted) + target gather (round-15 proven)
  fused_tail<<<dim3(NB_TAIL), 256, 0, stream>>>(
      hb, w0b, w1b, xb, hpb, head_b, y, idx0, idx1, n01, s0, s1, ht, tc);

  // per-row loss + mean (out[NROWS] pre-zeroed by conv_part)
  rowloss<<<dim3(NROWS / 256), 256, 0, stream>>>(
      hs, ht, s0, s1, tc, pos0, pos1, y, out);
}

// Round 19
// 96.700 us; speedup vs baseline: 1.1216x; 1.0113x over previous
//
#include <hip/hip_runtime.h>
#include <stdint.h>

#define NROWS 4096
#define NHID 1024
#define CC0 1675
#define CC1 5025
#define HEADSZ 1677
#define PD0 256
#define PD1 64
#define TSZ0 3350
#define TSZ1 45232
#define HPN (HEADSZ + PD0 + PD1)   // 1997: head + proj0 + proj1 fused B
#define TPC1 6
#define L2E 1.4426950408889634f
#define LN2 0.6931471805599453f

// fused_mid grid segmentation (segment starts divisible by 8)
#define NB_HD 896        // 14 colChunks x 64 rowBlks (64-row slim tiles)
#define NB_PJ 192        // 3 colChunks x 64 rowBlks (proj, N=320)
#define NB_CW 512        // w0/w1 bf16 conversion (grid-stride)
#define NB_MID (NB_HD + NB_PJ + NB_CW)

// fused_tail grid segmentation (round-15 proven: 44.7us)
#define NB_C1 1888       // 59 colChunks(tpc=6) x 32 rowBlks
#define NB_C0 864        // 27 colChunks x 32 rowBlks (compaction early-exit)
#define NB_TG 1024       // 4096 rows / 4 per block
#define NB_TAIL (NB_C1 + NB_C0 + NB_TG)

typedef __attribute__((ext_vector_type(8))) __bf16 bf16x8;
typedef __attribute__((ext_vector_type(4))) float f32x4;

__device__ __forceinline__ unsigned short f2bf(float f) {
  union { float f; uint32_t u; } v; v.f = f;
  return (unsigned short)((v.u + 0x7FFFu + ((v.u >> 16) & 1u)) >> 16);
}
__device__ __forceinline__ float bfl(uint32_t u) {
  union { uint32_t u; float f; } v; v.u = u << 16; return v.f;
}
__device__ __forceinline__ float bfh(uint32_t u) {
  union { uint32_t u; float f; } v; v.u = u & 0xFFFF0000u; return v.f;
}
__device__ __forceinline__ float bf1(unsigned short u) {
  union { uint32_t u; float f; } v; v.u = ((uint32_t)u) << 16; return v.f;
}
#define EXP2(x) __builtin_amdgcn_exp2f(x)

// ---- conversion ranges (float4 units, compile-time) ----
#define CV1 1048576                  // x
#define CV2 1477888                  // head_w (xL2E)
#define CV3 1543424                  // proj0
#define CV4 1559808                  // proj1
#define CV5 1774208                  // w0 (xL2E)
#define CV6 2497920                  // w1 (xL2E)
#define CVW0 (CV5 - CV4)             // 214400
#define CVW  (CV6 - CV4)             // 938112

// conv (blocks 0-1023) + row compaction (block 1024) + accumulator zeroing
__global__ void conv_part(const float* __restrict__ x, const float* __restrict__ hw,
                          const float* __restrict__ p0, const float* __restrict__ p1,
                          unsigned short* __restrict__ dst,
                          const int* __restrict__ y,
                          int* __restrict__ idx0, int* __restrict__ pos0,
                          int* __restrict__ idx1, int* __restrict__ pos1,
                          int* __restrict__ n01,
                          float* __restrict__ hs3, float* __restrict__ outp) {
  if (blockIdx.x >= 1025) {
    int z = blockIdx.x - 1025;               // [0,7)
    for (int i = z * 256 + (int)threadIdx.x; i < 3 * NROWS; i += 7 * 256)
      hs3[i] = 0.f;
    if (z == 0 && threadIdx.x == 0) outp[NROWS] = 0.f;
    return;
  }
  if (blockIdx.x == 1024) {
    __shared__ int sc0[256], sc1[256], nsh[2];
    int t = threadIdx.x;
    int yl[16];
    int c0 = 0, c1 = 0;
#pragma unroll
    for (int k = 0; k < 16; ++k) {
      int yv = y[t * 16 + k];
      yl[k] = yv;
      c0 += (yv >= CC0 && yv < CC1);
      c1 += (yv >= CC1);
    }
    sc0[t] = c0; sc1[t] = c1;
    __syncthreads();
    if (t == 0) {
      int a0 = 0, a1 = 0;
      for (int i = 0; i < 256; ++i) {
        int v0 = sc0[i]; sc0[i] = a0; a0 += v0;
        int v1 = sc1[i]; sc1[i] = a1; a1 += v1;
      }
      n01[0] = a0; n01[1] = a1; nsh[0] = a0; nsh[1] = a1;
    }
    __syncthreads();
    int p0c = sc0[t], p1c = sc1[t];
#pragma unroll
    for (int k = 0; k < 16; ++k) {
      int n = t * 16 + k, yv = yl[k];
      if (yv >= CC0 && yv < CC1) { idx0[p0c] = n; pos0[n] = p0c; ++p0c; }
      else if (yv >= CC1)        { idx1[p1c] = n; pos1[n] = p1c; ++p1c; }
    }
    for (int j = nsh[0] + t; j < NROWS; j += 256) idx0[j] = 0;
    for (int j = nsh[1] + t; j < NROWS; j += 256) idx1[j] = 0;
    return;
  }
  const int stride = 1024 * 256;
  for (int i = blockIdx.x * 256 + threadIdx.x; i < CV4; i += stride) {
    const float* src; int off; float sc;
    if (i < CV1)      { src = x;  off = i;       sc = 1.f; }
    else if (i < CV2) { src = hw; off = i - CV1; sc = L2E; }
    else if (i < CV3) { src = p0; off = i - CV2; sc = 1.f; }
    else              { src = p1; off = i - CV3; sc = 1.f; }
    float4 v = reinterpret_cast<const float4*>(src)[off];
    ushort4 o;
    o.x = f2bf(v.x * sc); o.y = f2bf(v.y * sc);
    o.z = f2bf(v.z * sc); o.w = f2bf(v.w * sc);
    reinterpret_cast<ushort4*>(dst)[i] = o;
  }
}

#define GLOAD(g, l) __builtin_amdgcn_global_load_lds( \
    (const __attribute__((address_space(1))) uint32_t*)(const void*)(g), \
    (__attribute__((address_space(3))) uint32_t*)(void*)(l), 16, 0, 0)

// Involution swizzle on byte offsets: XOR bits 4-6 with bits 7-9.
// Bank-verified (round 2): conflicts 0. Valid within 4KB/8KB subtiles.
#define SWZB(L) ((L) ^ ((((L) >> 7) & 7) << 4))

// --------------- 256-thread GEMM core (3-buffer counted ring) --------------
// Used by tail c0. gidx: optional A-row gather; nullptr = identity.
__device__ __forceinline__
void gemm_core(const unsigned short* __restrict__ A, int lda,
               const unsigned short* __restrict__ B, int ldb,
               int N, int K, int tile0, int tile1, int brow,
               const float* __restrict__ bias,
               float* __restrict__ sum_out,
               unsigned short* __restrict__ Cout, int ldc, int coutStart,
               unsigned short* AsB, unsigned short* BsB,
               const int* __restrict__ gidx) {
  const int tid = threadIdx.x;
  const int lane = tid & 63;
  const int wid = tid >> 6;
  const int wrow = (wid >> 1) * 64;
  const int wcol = (wid & 1) * 64;
  const int lr = lane & 15, lg = lane >> 4;
  const int nsteps = (tile1 - tile0) * (K >> 5);
  const int rowBase = brow + wrow;

  int arowc[2];
#pragma unroll
  for (int c = 0; c < 2; ++c) {
    int g = wid * 128 + c * 64 + lane;
    int S = SWZB(g * 16);
    int row = S >> 6;
    arowc[c] = gidx ? gidx[brow + row] : brow + row;
  }

  float sacc[4][4];
#pragma unroll
  for (int m = 0; m < 4; ++m)
#pragma unroll
    for (int r = 0; r < 4; ++r) sacc[m][r] = 0.f;

  auto stage = [&](int b, int tt, int kk) {
#pragma unroll
    for (int c = 0; c < 2; ++c) {
      int g = wid * 128 + c * 64 + lane;
      int L = g * 16;
      int S = SWZB(L);
      int row = S >> 6, ko = (S >> 4) & 3;
      GLOAD(A + (size_t)arowc[c] * lda + kk + ko * 8, (char*)AsB + b * 8192 + L);
      int bsrc = tt * 128 + row; bsrc = bsrc < N ? bsrc : N - 1;
      GLOAD(B + (size_t)bsrc * ldb + kk + ko * 8, (char*)BsB + b * 8192 + L);
    }
  };

  f32x4 acc[4][4];
#pragma unroll
  for (int m = 0; m < 4; ++m)
#pragma unroll
    for (int n = 0; n < 4; ++n) acc[m][n] = (f32x4){0.f, 0.f, 0.f, 0.f};

  int tp = tile0, kp = 0;
  auto adv = [&](int& t, int& k) { k += 32; if (k == K) { k = 0; ++t; } };
  stage(0, tp, kp); adv(tp, kp);
  if (nsteps > 1) { stage(1, tp, kp); adv(tp, kp); }

  int tile = tile0, k0 = 0;
  for (int s = 0; s < nsteps; ++s) {
    if (s + 1 < nsteps) asm volatile("s_waitcnt vmcnt(4)" ::: "memory");
    else                asm volatile("s_waitcnt vmcnt(0)" ::: "memory");
    __builtin_amdgcn_s_barrier();
    if (s + 2 < nsteps) { stage((s + 2) % 3, tp, kp); adv(tp, kp); }

    const int cur = s % 3;
    int k0n = k0 + 32, tn = tile;
    if (k0n == K) { k0n = 0; tn = tile + 1; }

    bf16x8 af[4], bfv[4];
#pragma unroll
    for (int m = 0; m < 4; ++m)
      af[m] = *(const bf16x8*)((const char*)AsB + cur * 8192 +
                               SWZB((wrow + m * 16 + lr) * 64 + lg * 16));
#pragma unroll
    for (int n = 0; n < 4; ++n)
      bfv[n] = *(const bf16x8*)((const char*)BsB + cur * 8192 +
                                SWZB((wcol + n * 16 + lr) * 64 + lg * 16));
#pragma unroll
    for (int m = 0; m < 4; ++m)
#pragma unroll
      for (int n = 0; n < 4; ++n)
        acc[m][n] = __builtin_amdgcn_mfma_f32_16x16x32_bf16(af[m], bfv[n], acc[m][n], 0, 0, 0);

    if (tn != tile) {
      const int cb = tile * 128 + wcol;
#pragma unroll
      for (int m = 0; m < 4; ++m)
#pragma unroll
        for (int n = 0; n < 4; ++n) {
#pragma unroll
          for (int r = 0; r < 4; ++r) {
            int col = cb + n * 16 + lr;
            if (col < N) {
              float v = acc[m][n][r];
              if (Cout && col >= coutStart) {
                int row = rowBase + m * 16 + lg * 4 + r;
                Cout[(size_t)row * ldc + (col - coutStart)] = f2bf(v);
              } else {
                if (bias) v = fmaf(bias[col], L2E, v);
                sacc[m][r] += EXP2(v);
              }
            }
          }
          acc[m][n] = (f32x4){0.f, 0.f, 0.f, 0.f};
        }
    }
    tile = tn; k0 = k0n;
  }

#pragma unroll
  for (int m = 0; m < 4; ++m)
#pragma unroll
    for (int r = 0; r < 4; ++r) {
      float s = sacc[m][r];
      s += __shfl_xor(s, 1); s += __shfl_xor(s, 2);
      s += __shfl_xor(s, 4); s += __shfl_xor(s, 8);
      if (lr == 0) atomicAdd(&sum_out[rowBase + m * 16 + lg * 4 + r], s);
    }
}

// ---- slim counted-ring GEMM core: 64 rows x 128 cols, BK=32, 3-buffer ----
// Tail-c1 schedule (T4 counted vmcnt) applied to the mid GEMMs: stage(s+2)
// issued after the barrier; vmcnt(3) waits only the oldest step (3 loads/
// thread/step: 1 A + 2 B). LDS: A 3x4KB + B 3x8KB = 36KB -> 4 blocks/CU.
__device__ __forceinline__
void gemm_core4(const unsigned short* __restrict__ A, int lda,
                const unsigned short* __restrict__ B, int ldb,
                int N, int K, int tile0, int brow,
                const float* __restrict__ bias,
                float* __restrict__ sum_out,
                unsigned short* __restrict__ Cout, int ldc,
                char* AsB, char* BsB) {
  const int tid = threadIdx.x;
  const int lane = tid & 63;
  const int wid = tid >> 6;
  const int wrow = (wid >> 1) * 32;    // 2 row halves of 32
  const int wcol = (wid & 1) * 64;     // 2 col halves of 64
  const int lr = lane & 15, lg = lane >> 4;
  const int nsteps = K >> 5;
  const int rowBase = brow + wrow;

  // per-thread pre-swizzled source coords (constant across steps)
  const int aL = tid * 16;             // A: 4KB, 1 chunk/thread
  const int aS = SWZB(aL);
  const int arow = aS >> 6, ako = ((aS >> 4) & 3) * 8;
  int bcol[2], bko[2];
#pragma unroll
  for (int c = 0; c < 2; ++c) {        // B: 8KB, 2 chunks/thread
    int L = (c * 256 + tid) * 16;
    int S = SWZB(L);
    int col = S >> 6;
    int bsrc = tile0 * 128 + col;
    bcol[c] = bsrc < N ? bsrc : N - 1;
    bko[c] = ((S >> 4) & 3) * 8;
  }

  auto stage = [&](int b, int kk) {
    GLOAD(A + (size_t)(brow + arow) * lda + kk + ako, AsB + b * 4096 + aL);
#pragma unroll
    for (int c = 0; c < 2; ++c)
      GLOAD(B + (size_t)bcol[c] * ldb + kk + bko[c],
            BsB + b * 8192 + (c * 256 + tid) * 16);
  };

  f32x4 acc[2][4];
#pragma unroll
  for (int m = 0; m < 2; ++m)
#pragma unroll
    for (int n = 0; n < 4; ++n) acc[m][n] = (f32x4){0.f, 0.f, 0.f, 0.f};

  stage(0, 0);
  stage(1, 32);

  for (int s = 0; s < nsteps; ++s) {
    if (s + 1 < nsteps) asm volatile("s_waitcnt vmcnt(3)" ::: "memory");
    else                asm volatile("s_waitcnt vmcnt(0)" ::: "memory");
    __builtin_amdgcn_s_barrier();
    if (s + 2 < nsteps) stage((s + 2) % 3, (s + 2) * 32);

    const int cur = s % 3;
    bf16x8 af[2], bfv[4];
#pragma unroll
    for (int m = 0; m < 2; ++m)
      af[m] = *(const bf16x8*)(AsB + cur * 4096 +
                               SWZB((wrow + m * 16 + lr) * 64 + lg * 16));
#pragma unroll
    for (int n = 0; n < 4; ++n)
      bfv[n] = *(const bf16x8*)(BsB + cur * 8192 +
                                SWZB((wcol + n * 16 + lr) * 64 + lg * 16));
#pragma unroll
    for (int m = 0; m < 2; ++m)
#pragma unroll
      for (int n = 0; n < 4; ++n)
        acc[m][n] = __builtin_amdgcn_mfma_f32_16x16x32_bf16(af[m], bfv[n], acc[m][n], 0, 0, 0);
  }

  const int cb = tile0 * 128 + wcol;
  float sacc[2][4];
#pragma unroll
  for (int m = 0; m < 2; ++m)
#pragma unroll
    for (int r = 0; r < 4; ++r) sacc[m][r] = 0.f;
#pragma unroll
  for (int m = 0; m < 2; ++m)
#pragma unroll
    for (int n = 0; n < 4; ++n)
#pragma unroll
      for (int r = 0; r < 4; ++r) {
        int col = cb + n * 16 + lr;
        if (col < N) {
          float v = acc[m][n][r];
          if (Cout) {
            int row = rowBase + m * 16 + lg * 4 + r;
            Cout[(size_t)row * ldc + col] = f2bf(v);
          } else {
            if (bias) v = fmaf(bias[col], L2E, v);
            sacc[m][r] += EXP2(v);
          }
        }
      }
  if (sum_out) {
#pragma unroll
    for (int m = 0; m < 2; ++m)
#pragma unroll
      for (int r = 0; r < 4; ++r) {
        float s = sacc[m][r];
        s += __shfl_xor(s, 1); s += __shfl_xor(s, 2);
        s += __shfl_xor(s, 4); s += __shfl_xor(s, 8);
        if (lr == 0) atomicAdd(&sum_out[rowBase + m * 16 + lg * 4 + r], s);
      }
  }
}

// ---- fused mid: head-sum | proj (slim counted ring) | w0/w1 conversion ----
__global__ __launch_bounds__(256, 4)
void fused_mid(const unsigned short* __restrict__ xb,
               const unsigned short* __restrict__ hpb,
               const float* __restrict__ head_b,
               float* __restrict__ hs,
               unsigned short* __restrict__ hb,
               const float* __restrict__ w0f, const float* __restrict__ w1f,
               unsigned short* __restrict__ dstAll) {
  __shared__ __align__(16) char lds[36864];   // A 3x4KB + B 3x8KB
  const int bid = blockIdx.x;

  if (bid < NB_HD) {
    // head exp2-sum: rowBlk-major XCD swizzle (A panels L2-local)
    const int xcd = bid & 7;
    const int local = bid >> 3;          // [0,112)
    const int rowBlk = xcd * 8 + local / 14;   // [0,64)
    const int colChunk = local % 14;
    gemm_core4(xb, NHID, hpb, NHID, HEADSZ, NHID, colChunk, rowBlk * 64,
               head_b, hs, nullptr, 0, lds, lds + 12288);
    return;
  }

  if (bid < NB_HD + NB_PJ) {
    // proj: hb = xb @ [proj0;proj1]^T, N=320, K=1024
    const int b1 = bid - NB_HD;
    const int cpx = NB_PJ >> 3;          // 24
    const int sid = (b1 & 7) * cpx + (b1 >> 3);
    const int rowBlk = sid & 63;         // [0,64)
    const int colChunk = sid >> 6;       // [0,3)
    gemm_core4(xb, NHID, hpb + (size_t)HEADSZ * NHID, NHID, PD0 + PD1, NHID,
               colChunk, rowBlk * 64,
               nullptr, nullptr, hb, PD0 + PD1, lds, lds + 12288);
    return;
  }

  // w0/w1 f32->bf16 conversion (xL2E), grid-stride
  {
    const int b2 = bid - NB_HD - NB_PJ;  // [0,512)
    const int stride = NB_CW * 256;
    for (int i = b2 * 256 + (int)threadIdx.x; i < CVW; i += stride) {
      const float* src; int off;
      if (i < CVW0) { src = w0f; off = i; }
      else          { src = w1f; off = i - CVW0; }
      float4 v = reinterpret_cast<const float4*>(src)[off];
      ushort4 o;
      o.x = f2bf(v.x * L2E); o.y = f2bf(v.y * L2E);
      o.z = f2bf(v.z * L2E); o.w = f2bf(v.w * L2E);
      reinterpret_cast<ushort4*>(dstAll)[CV4 + i] = o;
    }
  }
}

// -- fused tail: c1 (compacted) | c0 (compacted) | target gather ------------
// (byte-identical to round-15's measured 44.7us version)
__global__ __launch_bounds__(256, 3)
void fused_tail(const unsigned short* __restrict__ hb,
                const unsigned short* __restrict__ w0b,
                const unsigned short* __restrict__ w1b,
                const unsigned short* __restrict__ xb,
                const unsigned short* __restrict__ hwb,
                const float* __restrict__ head_b,
                const int* __restrict__ y,
                const int* __restrict__ idx0, const int* __restrict__ idx1,
                const int* __restrict__ n01,
                float* __restrict__ s0, float* __restrict__ s1,
                float* __restrict__ ht, float* __restrict__ tc) {
  __shared__ __align__(16) unsigned short lds[6 * 4096];   // 48KB union
  const int bid = blockIdx.x;

  if (bid < NB_C1) {
    // ---- cluster 1: hb[:,256:] @ w1^T (compacted rows), K=64 ----
    const int tid = threadIdx.x;
    const int lane = tid & 63;
    const int wid = tid >> 6;
    const int lr = lane & 15, lg = lane >> 4;
    const int cpx = NB_C1 >> 3;        // 236
    const int sid = (bid & 7) * cpx + (bid >> 3);
    const int rowBlk = sid & 31;
    const int colChunk = sid >> 5;     // [0,59)
    if (rowBlk * 128 >= n01[1]) return;          // compaction early-exit
    const int rowBase = rowBlk * 128 + (wid >> 1) * 64;
    const int wcol = (wid & 1) * 64;
    const int tile0 = colChunk * TPC1;

    int colOff[4], srcOff[4];
#pragma unroll
    for (int c = 0; c < 4; ++c) {
      int L = (c * 256 + tid) * 16;
      int S = L ^ (((L >> 7) & 7) << 4);
      colOff[c] = S >> 7;
      srcOff[c] = (S & 127) >> 1;
    }
    auto stage = [&](int b, int t) {
#pragma unroll
      for (int c = 0; c < 4; ++c) {
        int gc = t * 128 + colOff[c];
        gc = gc < TSZ1 ? gc : TSZ1 - 1;
        GLOAD(w1b + (size_t)gc * PD1 + srcOff[c],
              (char*)lds + b * 16384 + (c * 256 + tid) * 16);
      }
    };

    bf16x8 af[4][2];
#pragma unroll
    for (int m = 0; m < 4; ++m) {
      int ridx = idx1[rowBase + m * 16 + lr];    // gathered A row
      const unsigned short* p = hb + PD0 +
          (size_t)ridx * (PD0 + PD1) + lg * 8;
      af[m][0] = *(const bf16x8*)p;
      af[m][1] = *(const bf16x8*)(p + 32);
    }

    float sacc[4][4];
#pragma unroll
    for (int m = 0; m < 4; ++m)
#pragma unroll
      for (int r = 0; r < 4; ++r) sacc[m][r] = 0.f;

    stage(0, tile0);
    stage(1, tile0 + 1);

#pragma unroll 1
    for (int s = 0; s < TPC1; ++s) {
      if (s + 1 < TPC1) asm volatile("s_waitcnt vmcnt(4)" ::: "memory");
      else              asm volatile("s_waitcnt vmcnt(0)" ::: "memory");
      __builtin_amdgcn_s_barrier();
      if (s + 2 < TPC1) stage((s + 2) % 3, tile0 + s + 2);

      const int cur = s % 3;
      const int cb = (tile0 + s) * 128 + wcol;
      const int full = (cb + 63 < TSZ1);

#pragma unroll
      for (int nh = 0; nh < 2; ++nh) {
        bf16x8 bf[2][2];
#pragma unroll
        for (int nn = 0; nn < 2; ++nn) {
          int ccol = wcol + (nh * 2 + nn) * 16 + lr;
#pragma unroll
          for (int kh = 0; kh < 2; ++kh) {
            int L = ccol * 128 + kh * 64 + lg * 16;
            bf[nn][kh] = *(const bf16x8*)((const char*)lds + cur * 16384 +
                                          (L ^ ((ccol & 7) << 4)));
          }
        }
        f32x4 acc[4][2];
#pragma unroll
        for (int m = 0; m < 4; ++m)
#pragma unroll
          for (int nn = 0; nn < 2; ++nn) {
            f32x4 a = (f32x4){0.f, 0.f, 0.f, 0.f};
            a = __builtin_amdgcn_mfma_f32_16x16x32_bf16(af[m][0], bf[nn][0], a, 0, 0, 0);
            a = __builtin_amdgcn_mfma_f32_16x16x32_bf16(af[m][1], bf[nn][1], a, 0, 0, 0);
            acc[m][nn] = a;
          }
        if (full) {
#pragma unroll
          for (int m = 0; m < 4; ++m)
#pragma unroll
            for (int r = 0; r < 4; ++r)
              sacc[m][r] += EXP2(acc[m][0][r]) + EXP2(acc[m][1][r]);
        } else {
#pragma unroll
          for (int m = 0; m < 4; ++m)
#pragma unroll
            for (int r = 0; r < 4; ++r) {
              float t = 0.f;
#pragma unroll
              for (int nn = 0; nn < 2; ++nn)
                if (cb + (nh * 2 + nn) * 16 + lr < TSZ1) t += EXP2(acc[m][nn][r]);
              sacc[m][r] += t;
            }
        }
      }
    }

#pragma unroll
    for (int m = 0; m < 4; ++m)
#pragma unroll
      for (int r = 0; r < 4; ++r) {
        float s = sacc[m][r];
        s += __shfl_xor(s, 1); s += __shfl_xor(s, 2);
        s += __shfl_xor(s, 4); s += __shfl_xor(s, 8);
        if (lr == 0) atomicAdd(&s1[rowBase + m * 16 + lg * 4 + r], s);
      }
    return;
  }

  if (bid < NB_C1 + NB_C0) {
    // ---- cluster 0: hb[:, :256] @ w0^T (compacted rows), K=256 ----
    const int b0 = bid - NB_C1;
    const int cpx = NB_C0 >> 3;        // 108
    const int sid = (b0 & 7) * cpx + (b0 >> 3);
    const int rowBlk = sid & 31;
    const int colChunk = sid >> 5;     // [0,27)
    if (rowBlk * 128 >= n01[0]) return;          // compaction early-exit
    gemm_core(hb, PD0 + PD1, w0b, PD0, TSZ0, PD0, colChunk, colChunk + 1,
              rowBlk * 128, nullptr, s0, nullptr, 0, 0,
              (unsigned short*)lds, (unsigned short*)lds + 3 * 4096, idx0);
    return;
  }

  // ---- target logits: one wave per row, 4 rows per block ----
  {
    const int b2 = bid - NB_C1 - NB_C0;
    int row = b2 * 4 + (threadIdx.x >> 6);
    int lane = threadIdx.x & 63;
    int yv = y[row];
    int th = yv < CC0 ? yv : (yv < CC1 ? CC0 : CC0 + 1);

    const unsigned short* xr = xb + (size_t)row * NHID + lane * 16;
    const unsigned short* wr = hwb + (size_t)th * NHID + lane * 16;
    uint4 xa = *(const uint4*)xr,       wa = *(const uint4*)wr;
    uint4 xc = *(const uint4*)(xr + 8), wc = *(const uint4*)(wr + 8);
    float s = 0.f;
    uint32_t xs[8] = {xa.x, xa.y, xa.z, xa.w, xc.x, xc.y, xc.z, xc.w};
    uint32_t ws[8] = {wa.x, wa.y, wa.z, wa.w, wc.x, wc.y, wc.z, wc.w};
#pragma unroll
    for (int j = 0; j < 8; ++j)
      s += bfl(xs[j]) * bfl(ws[j]) + bfh(xs[j]) * bfh(ws[j]);
#pragma unroll
    for (int d = 1; d < 64; d <<= 1) s += __shfl_xor(s, d);

    float cl = 0.f;
    if (yv >= CC0) {
      if (yv < CC1) {
        int rel = yv - CC0;
        const unsigned short* hr = hb + (size_t)row * (PD0 + PD1) + lane * 4;
        const unsigned short* w0r = w0b + (size_t)rel * PD0 + lane * 4;
        uint2 ha = *(const uint2*)hr, wa0 = *(const uint2*)w0r;
        cl = bfl(ha.x) * bfl(wa0.x) + bfh(ha.x) * bfh(wa0.x)
           + bfl(ha.y) * bfl(wa0.y) + bfh(ha.y) * bfh(wa0.y);
      } else {
        int rel = yv - CC1;
        cl = bf1(hb[(size_t)row * (PD0 + PD1) + PD0 + lane])
           * bf1(w1b[(size_t)rel * PD1 + lane]);
      }
#pragma unroll
      for (int d = 1; d < 64; d <<= 1) cl += __shfl_xor(cl, d);
    }
    if (lane == 0) { ht[row] = s * LN2 + head_b[th]; tc[row] = (yv < CC0) ? 0.f : cl; }
  }
}

// Per-row loss + parallel mean reduction. out[NROWS] pre-zeroed (conv_part).
__global__ void rowloss(const float* __restrict__ hs, const float* __restrict__ ht,
                        const float* __restrict__ s0, const float* __restrict__ s1,
                        const float* __restrict__ tc,
                        const int* __restrict__ pos0, const int* __restrict__ pos1,
                        const int* __restrict__ y, float* __restrict__ out) {
  int n = blockIdx.x * 256 + threadIdx.x;
  int yv = y[n];
  float o = ht[n] - __builtin_amdgcn_logf(hs[n]) * LN2;
  if (yv >= CC0) {
    float sv = (yv < CC1) ? s0[pos0[n]] : s1[pos1[n]];
    o += tc[n] * LN2 - __builtin_amdgcn_logf(sv) * LN2;
  }
  out[n] = o;
  float l = o;
#pragma unroll
  for (int d = 1; d < 64; d <<= 1) l += __shfl_xor(l, d);
  __shared__ float red[4];
  if ((threadIdx.x & 63) == 0) red[threadIdx.x >> 6] = l;
  __syncthreads();
  if (threadIdx.x == 0)
    atomicAdd(&out[NROWS], -(red[0] + red[1] + red[2] + red[3]) / (float)NROWS);
}

extern "C" void kernel_launch(void* const* d_in, const int* in_sizes, int n_in,
                              void* d_out, int out_size, void* d_ws, size_t ws_size,
                              hipStream_t stream) {
  const float* x      = (const float*)d_in[0];
  const int*   y      = (const int*)d_in[1];
  const float* head_w = (const float*)d_in[2];
  const float* head_b = (const float*)d_in[3];
  const float* proj0  = (const float*)d_in[4];
  const float* w0     = (const float*)d_in[5];
  const float* proj1  = (const float*)d_in[6];
  const float* w1     = (const float*)d_in[7];
  float* out = (float*)d_out;

  char* wp = (char*)d_ws;
  unsigned short* xb  = (unsigned short*)wp; wp += (size_t)NROWS * NHID * 2;
  unsigned short* hpb = (unsigned short*)wp; wp += (size_t)HPN * NHID * 2;
  unsigned short* w0b = (unsigned short*)wp; wp += (size_t)TSZ0 * PD0 * 2;
  unsigned short* w1b = (unsigned short*)wp; wp += (size_t)TSZ1 * PD1 * 2;
  unsigned short* hb  = (unsigned short*)wp; wp += (size_t)NROWS * (PD0 + PD1) * 2;
  float* hs = (float*)wp; wp += NROWS * 4;
  float* s0 = (float*)wp; wp += NROWS * 4;
  float* s1 = (float*)wp; wp += NROWS * 4;
  float* ht = (float*)wp; wp += NROWS * 4;
  float* tc = (float*)wp; wp += NROWS * 4;
  int* idx0 = (int*)wp; wp += NROWS * 4;
  int* pos0 = (int*)wp; wp += NROWS * 4;
  int* idx1 = (int*)wp; wp += NROWS * 4;
  int* pos1 = (int*)wp; wp += NROWS * 4;
  int* n01  = (int*)wp; wp += 8 * 4;

  // conv + compaction + accumulator zeroing (no separate memsets)
  conv_part<<<dim3(1032), 256, 0, stream>>>(
      x, head_w, proj0, proj1, xb, y, idx0, pos0, idx1, pos1, n01, hs, out);

  // fused mid: head-sum + proj (slim counted ring, 4/CU) + w0/w1 conversion
  fused_mid<<<dim3(NB_MID), 256, 0, stream>>>(
      xb, hpb, head_b, hs, hb, w0, w1, xb);

  // fused tail: c1 + c0 (compacted) + target gather (round-15 proven)
  fused_tail<<<dim3(NB_TAIL), 256, 0, stream>>>(
      hb, w0b, w1b, xb, hpb, head_b, y, idx0, idx1, n01, s0, s1, ht, tc);

  // per-row loss + mean (out[NROWS] pre-zeroed by conv_part)
  rowloss<<<dim3(NROWS / 256), 256, 0, stream>>>(
      hs, ht, s0, s1, tc, pos0, pos1, y, out);
}

// Round 20
// 92.754 us; speedup vs baseline: 1.1693x; 1.0426x over previous
//
#include <hip/hip_runtime.h>
#include <stdint.h>

#define NROWS 4096
#define NHID 1024
#define CC0 1675
#define CC1 5025
#define HEADSZ 1677
#define PD0 256
#define PD1 64
#define TSZ0 3350
#define TSZ1 45232
#define HPN (HEADSZ + PD0 + PD1)   // 1997: head + proj0 + proj1 fused B
#define TPC1 6
#define L2E 1.4426950408889634f
#define LN2 0.6931471805599453f

// proj_mid: 3 colChunks x 64 rowBlks (slim 64x128 tiles)
#define NB_PJ 192

// fused_tail grid segmentation (segment starts divisible by 8; head first)
#define NB_HD 896        // 14 colChunks x 64 rowBlks (slim head)
#define NB_C1 1888       // 59 colChunks(tpc=6) x 32 rowBlks (compacted)
#define NB_C0 864        // 27 colChunks x 32 rowBlks (compacted)
#define NB_TG 1024       // 4096 rows / 4 per block
#define NB_TAIL (NB_HD + NB_C1 + NB_C0 + NB_TG)

typedef __attribute__((ext_vector_type(8))) __bf16 bf16x8;
typedef __attribute__((ext_vector_type(4))) float f32x4;

__device__ __forceinline__ unsigned short f2bf(float f) {
  union { float f; uint32_t u; } v; v.f = f;
  return (unsigned short)((v.u + 0x7FFFu + ((v.u >> 16) & 1u)) >> 16);
}
__device__ __forceinline__ float bfl(uint32_t u) {
  union { uint32_t u; float f; } v; v.u = u << 16; return v.f;
}
__device__ __forceinline__ float bfh(uint32_t u) {
  union { uint32_t u; float f; } v; v.u = u & 0xFFFF0000u; return v.f;
}
__device__ __forceinline__ float bf1(unsigned short u) {
  union { uint32_t u; float f; } v; v.u = ((uint32_t)u) << 16; return v.f;
}
#define EXP2(x) __builtin_amdgcn_exp2f(x)

// ---- conversion ranges (float4 units, compile-time) ----
#define CV1 1048576                  // x
#define CV2 1477888                  // head_w (xL2E)
#define CV3 1543424                  // proj0
#define CV4 1559808                  // proj1
#define CV5 1774208                  // w0 (xL2E)
#define CV6 2497920                  // w1 (xL2E)

// conv of ALL tensors (blocks 0-1023) + compaction (1024) + zeroing (1025+)
__global__ void conv_part(const float* __restrict__ x, const float* __restrict__ hw,
                          const float* __restrict__ p0, const float* __restrict__ p1,
                          const float* __restrict__ w0, const float* __restrict__ w1,
                          unsigned short* __restrict__ dst,
                          const int* __restrict__ y,
                          int* __restrict__ idx0, int* __restrict__ pos0,
                          int* __restrict__ idx1, int* __restrict__ pos1,
                          int* __restrict__ n01,
                          float* __restrict__ hs3, float* __restrict__ outp) {
  if (blockIdx.x >= 1025) {
    int z = blockIdx.x - 1025;               // [0,7)
    for (int i = z * 256 + (int)threadIdx.x; i < 3 * NROWS; i += 7 * 256)
      hs3[i] = 0.f;
    if (z == 0 && threadIdx.x == 0) outp[NROWS] = 0.f;
    return;
  }
  if (blockIdx.x == 1024) {
    __shared__ int sc0[256], sc1[256], nsh[2];
    int t = threadIdx.x;
    int yl[16];
    int c0 = 0, c1 = 0;
#pragma unroll
    for (int k = 0; k < 16; ++k) {
      int yv = y[t * 16 + k];
      yl[k] = yv;
      c0 += (yv >= CC0 && yv < CC1);
      c1 += (yv >= CC1);
    }
    sc0[t] = c0; sc1[t] = c1;
    __syncthreads();
    if (t == 0) {
      int a0 = 0, a1 = 0;
      for (int i = 0; i < 256; ++i) {
        int v0 = sc0[i]; sc0[i] = a0; a0 += v0;
        int v1 = sc1[i]; sc1[i] = a1; a1 += v1;
      }
      n01[0] = a0; n01[1] = a1; nsh[0] = a0; nsh[1] = a1;
    }
    __syncthreads();
    int p0c = sc0[t], p1c = sc1[t];
#pragma unroll
    for (int k = 0; k < 16; ++k) {
      int n = t * 16 + k, yv = yl[k];
      if (yv >= CC0 && yv < CC1) { idx0[p0c] = n; pos0[n] = p0c; ++p0c; }
      else if (yv >= CC1)        { idx1[p1c] = n; pos1[n] = p1c; ++p1c; }
    }
    for (int j = nsh[0] + t; j < NROWS; j += 256) idx0[j] = 0;
    for (int j = nsh[1] + t; j < NROWS; j += 256) idx1[j] = 0;
    return;
  }
  const int stride = 1024 * 256;
  for (int i = blockIdx.x * 256 + threadIdx.x; i < CV6; i += stride) {
    const float* src; int off; float sc;
    if (i < CV1)      { src = x;  off = i;       sc = 1.f; }
    else if (i < CV2) { src = hw; off = i - CV1; sc = L2E; }
    else if (i < CV3) { src = p0; off = i - CV2; sc = 1.f; }
    else if (i < CV4) { src = p1; off = i - CV3; sc = 1.f; }
    else if (i < CV5) { src = w0; off = i - CV4; sc = L2E; }
    else              { src = w1; off = i - CV5; sc = L2E; }
    float4 v = reinterpret_cast<const float4*>(src)[off];
    ushort4 o;
    o.x = f2bf(v.x * sc); o.y = f2bf(v.y * sc);
    o.z = f2bf(v.z * sc); o.w = f2bf(v.w * sc);
    reinterpret_cast<ushort4*>(dst)[i] = o;
  }
}

#define GLOAD(g, l) __builtin_amdgcn_global_load_lds( \
    (const __attribute__((address_space(1))) uint32_t*)(const void*)(g), \
    (__attribute__((address_space(3))) uint32_t*)(void*)(l), 16, 0, 0)

// Involution swizzle on byte offsets: XOR bits 4-6 with bits 7-9.
// Bank-verified (round 2): conflicts 0. Valid within 4KB/8KB subtiles.
#define SWZB(L) ((L) ^ ((((L) >> 7) & 7) << 4))

// --------------- 256-thread GEMM core (3-buffer counted ring) --------------
// Used by tail c0. gidx: optional A-row gather; nullptr = identity.
__device__ __forceinline__
void gemm_core(const unsigned short* __restrict__ A, int lda,
               const unsigned short* __restrict__ B, int ldb,
               int N, int K, int tile0, int tile1, int brow,
               const float* __restrict__ bias,
               float* __restrict__ sum_out,
               unsigned short* __restrict__ Cout, int ldc, int coutStart,
               unsigned short* AsB, unsigned short* BsB,
               const int* __restrict__ gidx) {
  const int tid = threadIdx.x;
  const int lane = tid & 63;
  const int wid = tid >> 6;
  const int wrow = (wid >> 1) * 64;
  const int wcol = (wid & 1) * 64;
  const int lr = lane & 15, lg = lane >> 4;
  const int nsteps = (tile1 - tile0) * (K >> 5);
  const int rowBase = brow + wrow;

  int arowc[2];
#pragma unroll
  for (int c = 0; c < 2; ++c) {
    int g = wid * 128 + c * 64 + lane;
    int S = SWZB(g * 16);
    int row = S >> 6;
    arowc[c] = gidx ? gidx[brow + row] : brow + row;
  }

  float sacc[4][4];
#pragma unroll
  for (int m = 0; m < 4; ++m)
#pragma unroll
    for (int r = 0; r < 4; ++r) sacc[m][r] = 0.f;

  auto stage = [&](int b, int tt, int kk) {
#pragma unroll
    for (int c = 0; c < 2; ++c) {
      int g = wid * 128 + c * 64 + lane;
      int L = g * 16;
      int S = SWZB(L);
      int row = S >> 6, ko = (S >> 4) & 3;
      GLOAD(A + (size_t)arowc[c] * lda + kk + ko * 8, (char*)AsB + b * 8192 + L);
      int bsrc = tt * 128 + row; bsrc = bsrc < N ? bsrc : N - 1;
      GLOAD(B + (size_t)bsrc * ldb + kk + ko * 8, (char*)BsB + b * 8192 + L);
    }
  };

  f32x4 acc[4][4];
#pragma unroll
  for (int m = 0; m < 4; ++m)
#pragma unroll
    for (int n = 0; n < 4; ++n) acc[m][n] = (f32x4){0.f, 0.f, 0.f, 0.f};

  int tp = tile0, kp = 0;
  auto adv = [&](int& t, int& k) { k += 32; if (k == K) { k = 0; ++t; } };
  stage(0, tp, kp); adv(tp, kp);
  if (nsteps > 1) { stage(1, tp, kp); adv(tp, kp); }

  int tile = tile0, k0 = 0;
  for (int s = 0; s < nsteps; ++s) {
    if (s + 1 < nsteps) asm volatile("s_waitcnt vmcnt(4)" ::: "memory");
    else                asm volatile("s_waitcnt vmcnt(0)" ::: "memory");
    __builtin_amdgcn_s_barrier();
    if (s + 2 < nsteps) { stage((s + 2) % 3, tp, kp); adv(tp, kp); }

    const int cur = s % 3;
    int k0n = k0 + 32, tn = tile;
    if (k0n == K) { k0n = 0; tn = tile + 1; }

    bf16x8 af[4], bfv[4];
#pragma unroll
    for (int m = 0; m < 4; ++m)
      af[m] = *(const bf16x8*)((const char*)AsB + cur * 8192 +
                               SWZB((wrow + m * 16 + lr) * 64 + lg * 16));
#pragma unroll
    for (int n = 0; n < 4; ++n)
      bfv[n] = *(const bf16x8*)((const char*)BsB + cur * 8192 +
                                SWZB((wcol + n * 16 + lr) * 64 + lg * 16));
#pragma unroll
    for (int m = 0; m < 4; ++m)
#pragma unroll
      for (int n = 0; n < 4; ++n)
        acc[m][n] = __builtin_amdgcn_mfma_f32_16x16x32_bf16(af[m], bfv[n], acc[m][n], 0, 0, 0);

    if (tn != tile) {
      const int cb = tile * 128 + wcol;
#pragma unroll
      for (int m = 0; m < 4; ++m)
#pragma unroll
        for (int n = 0; n < 4; ++n) {
#pragma unroll
          for (int r = 0; r < 4; ++r) {
            int col = cb + n * 16 + lr;
            if (col < N) {
              float v = acc[m][n][r];
              if (Cout && col >= coutStart) {
                int row = rowBase + m * 16 + lg * 4 + r;
                Cout[(size_t)row * ldc + (col - coutStart)] = f2bf(v);
              } else {
                if (bias) v = fmaf(bias[col], L2E, v);
                sacc[m][r] += EXP2(v);
              }
            }
          }
          acc[m][n] = (f32x4){0.f, 0.f, 0.f, 0.f};
        }
    }
    tile = tn; k0 = k0n;
  }

#pragma unroll
  for (int m = 0; m < 4; ++m)
#pragma unroll
    for (int r = 0; r < 4; ++r) {
      float s = sacc[m][r];
      s += __shfl_xor(s, 1); s += __shfl_xor(s, 2);
      s += __shfl_xor(s, 4); s += __shfl_xor(s, 8);
      if (lr == 0) atomicAdd(&sum_out[rowBase + m * 16 + lg * 4 + r], s);
    }
}

// ---- slim counted-ring GEMM core: 64 rows x 128 cols, BK=32, 3-buffer ----
// stage(s+2) issued after the barrier; vmcnt(3) waits only the oldest step.
// LDS: A 3x4KB + B 3x8KB = 36KB.
__device__ __forceinline__
void gemm_core4(const unsigned short* __restrict__ A, int lda,
                const unsigned short* __restrict__ B, int ldb,
                int N, int K, int tile0, int brow,
                const float* __restrict__ bias,
                float* __restrict__ sum_out,
                unsigned short* __restrict__ Cout, int ldc,
                char* AsB, char* BsB) {
  const int tid = threadIdx.x;
  const int lane = tid & 63;
  const int wid = tid >> 6;
  const int wrow = (wid >> 1) * 32;
  const int wcol = (wid & 1) * 64;
  const int lr = lane & 15, lg = lane >> 4;
  const int nsteps = K >> 5;
  const int rowBase = brow + wrow;

  const int aL = tid * 16;
  const int aS = SWZB(aL);
  const int arow = aS >> 6, ako = ((aS >> 4) & 3) * 8;
  int bcol[2], bko[2];
#pragma unroll
  for (int c = 0; c < 2; ++c) {
    int L = (c * 256 + tid) * 16;
    int S = SWZB(L);
    int col = S >> 6;
    int bsrc = tile0 * 128 + col;
    bcol[c] = bsrc < N ? bsrc : N - 1;
    bko[c] = ((S >> 4) & 3) * 8;
  }

  auto stage = [&](int b, int kk) {
    GLOAD(A + (size_t)(brow + arow) * lda + kk + ako, AsB + b * 4096 + aL);
#pragma unroll
    for (int c = 0; c < 2; ++c)
      GLOAD(B + (size_t)bcol[c] * ldb + kk + bko[c],
            BsB + b * 8192 + (c * 256 + tid) * 16);
  };

  f32x4 acc[2][4];
#pragma unroll
  for (int m = 0; m < 2; ++m)
#pragma unroll
    for (int n = 0; n < 4; ++n) acc[m][n] = (f32x4){0.f, 0.f, 0.f, 0.f};

  stage(0, 0);
  stage(1, 32);

  for (int s = 0; s < nsteps; ++s) {
    if (s + 1 < nsteps) asm volatile("s_waitcnt vmcnt(3)" ::: "memory");
    else                asm volatile("s_waitcnt vmcnt(0)" ::: "memory");
    __builtin_amdgcn_s_barrier();
    if (s + 2 < nsteps) stage((s + 2) % 3, (s + 2) * 32);

    const int cur = s % 3;
    bf16x8 af[2], bfv[4];
#pragma unroll
    for (int m = 0; m < 2; ++m)
      af[m] = *(const bf16x8*)(AsB + cur * 4096 +
                               SWZB((wrow + m * 16 + lr) * 64 + lg * 16));
#pragma unroll
    for (int n = 0; n < 4; ++n)
      bfv[n] = *(const bf16x8*)(BsB + cur * 8192 +
                                SWZB((wcol + n * 16 + lr) * 64 + lg * 16));
#pragma unroll
    for (int m = 0; m < 2; ++m)
#pragma unroll
      for (int n = 0; n < 4; ++n)
        acc[m][n] = __builtin_amdgcn_mfma_f32_16x16x32_bf16(af[m], bfv[n], acc[m][n], 0, 0, 0);
  }

  const int cb = tile0 * 128 + wcol;
  float sacc[2][4];
#pragma unroll
  for (int m = 0; m < 2; ++m)
#pragma unroll
    for (int r = 0; r < 4; ++r) sacc[m][r] = 0.f;
#pragma unroll
  for (int m = 0; m < 2; ++m)
#pragma unroll
    for (int n = 0; n < 4; ++n)
#pragma unroll
      for (int r = 0; r < 4; ++r) {
        int col = cb + n * 16 + lr;
        if (col < N) {
          float v = acc[m][n][r];
          if (Cout) {
            int row = rowBase + m * 16 + lg * 4 + r;
            Cout[(size_t)row * ldc + col] = f2bf(v);
          } else {
            if (bias) v = fmaf(bias[col], L2E, v);
            sacc[m][r] += EXP2(v);
          }
        }
      }
  if (sum_out) {
#pragma unroll
    for (int m = 0; m < 2; ++m)
#pragma unroll
      for (int r = 0; r < 4; ++r) {
        float s = sacc[m][r];
        s += __shfl_xor(s, 1); s += __shfl_xor(s, 2);
        s += __shfl_xor(s, 4); s += __shfl_xor(s, 8);
        if (lr == 0) atomicAdd(&sum_out[rowBase + m * 16 + lg * 4 + r], s);
      }
  }
}

// ---- proj mid: hb = xb @ [proj0;proj1]^T only (192 slim blocks) -----------
__global__ __launch_bounds__(256, 4)
void proj_mid(const unsigned short* __restrict__ xb,
              const unsigned short* __restrict__ hpb,
              unsigned short* __restrict__ hb) {
  __shared__ __align__(16) char lds[36864];
  const int bid = blockIdx.x;
  const int cpx = NB_PJ >> 3;          // 24
  const int sid = (bid & 7) * cpx + (bid >> 3);
  const int rowBlk = sid & 63;         // [0,64)
  const int colChunk = sid >> 6;       // [0,3)
  gemm_core4(xb, NHID, hpb + (size_t)HEADSZ * NHID, NHID, PD0 + PD1, NHID,
             colChunk, rowBlk * 64,
             nullptr, nullptr, hb, PD0 + PD1, lds, lds + 12288);
}

// -- fused tail: head (slim) | c1 (compacted) | c0 (compacted) | target -----
// Head blocks first: they pin CUs ~20us while c1/c0/tg fill behind.
__global__ __launch_bounds__(256, 3)
void fused_tail(const unsigned short* __restrict__ hb,
                const unsigned short* __restrict__ w0b,
                const unsigned short* __restrict__ w1b,
                const unsigned short* __restrict__ xb,
                const unsigned short* __restrict__ hwb,
                const float* __restrict__ head_b,
                const int* __restrict__ y,
                const int* __restrict__ idx0, const int* __restrict__ idx1,
                const int* __restrict__ n01,
                float* __restrict__ hs,
                float* __restrict__ s0, float* __restrict__ s1,
                float* __restrict__ ht, float* __restrict__ tc) {
  __shared__ __align__(16) unsigned short lds[6 * 4096];   // 48KB union
  const int bid = blockIdx.x;

  if (bid < NB_HD) {
    // ---- head exp2-sum: slim counted ring, rowBlk-major XCD swizzle ----
    const int xcd = bid & 7;
    const int local = bid >> 3;          // [0,112)
    const int rowBlk = xcd * 8 + local / 14;   // [0,64)
    const int colChunk = local % 14;
    gemm_core4(xb, NHID, hwb, NHID, HEADSZ, NHID, colChunk, rowBlk * 64,
               head_b, hs, nullptr, 0, (char*)lds, (char*)lds + 12288);
    return;
  }

  if (bid < NB_HD + NB_C1) {
    // ---- cluster 1: hb[:,256:] @ w1^T (compacted rows), K=64 ----
    const int b1 = bid - NB_HD;
    const int tid = threadIdx.x;
    const int lane = tid & 63;
    const int wid = tid >> 6;
    const int lr = lane & 15, lg = lane >> 4;
    const int cpx = NB_C1 >> 3;        // 236
    const int sid = (b1 & 7) * cpx + (b1 >> 3);
    const int rowBlk = sid & 31;
    const int colChunk = sid >> 5;     // [0,59)
    if (rowBlk * 128 >= n01[1]) return;          // compaction early-exit
    const int rowBase = rowBlk * 128 + (wid >> 1) * 64;
    const int wcol = (wid & 1) * 64;
    const int tile0 = colChunk * TPC1;

    int colOff[4], srcOff[4];
#pragma unroll
    for (int c = 0; c < 4; ++c) {
      int L = (c * 256 + tid) * 16;
      int S = L ^ (((L >> 7) & 7) << 4);
      colOff[c] = S >> 7;
      srcOff[c] = (S & 127) >> 1;
    }
    auto stage = [&](int b, int t) {
#pragma unroll
      for (int c = 0; c < 4; ++c) {
        int gc = t * 128 + colOff[c];
        gc = gc < TSZ1 ? gc : TSZ1 - 1;
        GLOAD(w1b + (size_t)gc * PD1 + srcOff[c],
              (char*)lds + b * 16384 + (c * 256 + tid) * 16);
      }
    };

    bf16x8 af[4][2];
#pragma unroll
    for (int m = 0; m < 4; ++m) {
      int ridx = idx1[rowBase + m * 16 + lr];    // gathered A row
      const unsigned short* p = hb + PD0 +
          (size_t)ridx * (PD0 + PD1) + lg * 8;
      af[m][0] = *(const bf16x8*)p;
      af[m][1] = *(const bf16x8*)(p + 32);
    }

    float sacc[4][4];
#pragma unroll
    for (int m = 0; m < 4; ++m)
#pragma unroll
      for (int r = 0; r < 4; ++r) sacc[m][r] = 0.f;

    stage(0, tile0);
    stage(1, tile0 + 1);

#pragma unroll 1
    for (int s = 0; s < TPC1; ++s) {
      if (s + 1 < TPC1) asm volatile("s_waitcnt vmcnt(4)" ::: "memory");
      else              asm volatile("s_waitcnt vmcnt(0)" ::: "memory");
      __builtin_amdgcn_s_barrier();
      if (s + 2 < TPC1) stage((s + 2) % 3, tile0 + s + 2);

      const int cur = s % 3;
      const int cb = (tile0 + s) * 128 + wcol;
      const int full = (cb + 63 < TSZ1);

#pragma unroll
      for (int nh = 0; nh < 2; ++nh) {
        bf16x8 bf[2][2];
#pragma unroll
        for (int nn = 0; nn < 2; ++nn) {
          int ccol = wcol + (nh * 2 + nn) * 16 + lr;
#pragma unroll
          for (int kh = 0; kh < 2; ++kh) {
            int L = ccol * 128 + kh * 64 + lg * 16;
            bf[nn][kh] = *(const bf16x8*)((const char*)lds + cur * 16384 +
                                          (L ^ ((ccol & 7) << 4)));
          }
        }
        f32x4 acc[4][2];
#pragma unroll
        for (int m = 0; m < 4; ++m)
#pragma unroll
          for (int nn = 0; nn < 2; ++nn) {
            f32x4 a = (f32x4){0.f, 0.f, 0.f, 0.f};
            a = __builtin_amdgcn_mfma_f32_16x16x32_bf16(af[m][0], bf[nn][0], a, 0, 0, 0);
            a = __builtin_amdgcn_mfma_f32_16x16x32_bf16(af[m][1], bf[nn][1], a, 0, 0, 0);
            acc[m][nn] = a;
          }
        if (full) {
#pragma unroll
          for (int m = 0; m < 4; ++m)
#pragma unroll
            for (int r = 0; r < 4; ++r)
              sacc[m][r] += EXP2(acc[m][0][r]) + EXP2(acc[m][1][r]);
        } else {
#pragma unroll
          for (int m = 0; m < 4; ++m)
#pragma unroll
            for (int r = 0; r < 4; ++r) {
              float t = 0.f;
#pragma unroll
              for (int nn = 0; nn < 2; ++nn)
                if (cb + (nh * 2 + nn) * 16 + lr < TSZ1) t += EXP2(acc[m][nn][r]);
              sacc[m][r] += t;
            }
        }
      }
    }

#pragma unroll
    for (int m = 0; m < 4; ++m)
#pragma unroll
      for (int r = 0; r < 4; ++r) {
        float s = sacc[m][r];
        s += __shfl_xor(s, 1); s += __shfl_xor(s, 2);
        s += __shfl_xor(s, 4); s += __shfl_xor(s, 8);
        if (lr == 0) atomicAdd(&s1[rowBase + m * 16 + lg * 4 + r], s);
      }
    return;
  }

  if (bid < NB_HD + NB_C1 + NB_C0) {
    // ---- cluster 0: hb[:, :256] @ w0^T (compacted rows), K=256 ----
    const int b0 = bid - NB_HD - NB_C1;
    const int cpx = NB_C0 >> 3;        // 108
    const int sid = (b0 & 7) * cpx + (b0 >> 3);
    const int rowBlk = sid & 31;
    const int colChunk = sid >> 5;     // [0,27)
    if (rowBlk * 128 >= n01[0]) return;          // compaction early-exit
    gemm_core(hb, PD0 + PD1, w0b, PD0, TSZ0, PD0, colChunk, colChunk + 1,
              rowBlk * 128, nullptr, s0, nullptr, 0, 0,
              (unsigned short*)lds, (unsigned short*)lds + 3 * 4096, idx0);
    return;
  }

  // ---- target logits: one wave per row, 4 rows per block ----
  {
    const int b2 = bid - NB_HD - NB_C1 - NB_C0;
    int row = b2 * 4 + (threadIdx.x >> 6);
    int lane = threadIdx.x & 63;
    int yv = y[row];
    int th = yv < CC0 ? yv : (yv < CC1 ? CC0 : CC0 + 1);

    const unsigned short* xr = xb + (size_t)row * NHID + lane * 16;
    const unsigned short* wr = hwb + (size_t)th * NHID + lane * 16;
    uint4 xa = *(const uint4*)xr,       wa = *(const uint4*)wr;
    uint4 xc = *(const uint4*)(xr + 8), wc = *(const uint4*)(wr + 8);
    float s = 0.f;
    uint32_t xs[8] = {xa.x, xa.y, xa.z, xa.w, xc.x, xc.y, xc.z, xc.w};
    uint32_t ws[8] = {wa.x, wa.y, wa.z, wa.w, wc.x, wc.y, wc.z, wc.w};
#pragma unroll
    for (int j = 0; j < 8; ++j)
      s += bfl(xs[j]) * bfl(ws[j]) + bfh(xs[j]) * bfh(ws[j]);
#pragma unroll
    for (int d = 1; d < 64; d <<= 1) s += __shfl_xor(s, d);

    float cl = 0.f;
    if (yv >= CC0) {
      if (yv < CC1) {
        int rel = yv - CC0;
        const unsigned short* hr = hb + (size_t)row * (PD0 + PD1) + lane * 4;
        const unsigned short* w0r = w0b + (size_t)rel * PD0 + lane * 4;
        uint2 ha = *(const uint2*)hr, wa0 = *(const uint2*)w0r;
        cl = bfl(ha.x) * bfl(wa0.x) + bfh(ha.x) * bfh(wa0.x)
           + bfl(ha.y) * bfl(wa0.y) + bfh(ha.y) * bfh(wa0.y);
      } else {
        int rel = yv - CC1;
        cl = bf1(hb[(size_t)row * (PD0 + PD1) + PD0 + lane])
           * bf1(w1b[(size_t)rel * PD1 + lane]);
      }
#pragma unroll
      for (int d = 1; d < 64; d <<= 1) cl += __shfl_xor(cl, d);
    }
    if (lane == 0) { ht[row] = s * LN2 + head_b[th]; tc[row] = (yv < CC0) ? 0.f : cl; }
  }
}

// Per-row loss + parallel mean reduction. out[NROWS] pre-zeroed (conv_part).
__global__ void rowloss(const float* __restrict__ hs, const float* __restrict__ ht,
                        const float* __restrict__ s0, const float* __restrict__ s1,
                        const float* __restrict__ tc,
                        const int* __restrict__ pos0, const int* __restrict__ pos1,
                        const int* __restrict__ y, float* __restrict__ out) {
  int n = blockIdx.x * 256 + threadIdx.x;
  int yv = y[n];
  float o = ht[n] - __builtin_amdgcn_logf(hs[n]) * LN2;
  if (yv >= CC0) {
    float sv = (yv < CC1) ? s0[pos0[n]] : s1[pos1[n]];
    o += tc[n] * LN2 - __builtin_amdgcn_logf(sv) * LN2;
  }
  out[n] = o;
  float l = o;
#pragma unroll
  for (int d = 1; d < 64; d <<= 1) l += __shfl_xor(l, d);
  __shared__ float red[4];
  if ((threadIdx.x & 63) == 0) red[threadIdx.x >> 6] = l;
  __syncthreads();
  if (threadIdx.x == 0)
    atomicAdd(&out[NROWS], -(red[0] + red[1] + red[2] + red[3]) / (float)NROWS);
}

extern "C" void kernel_launch(void* const* d_in, const int* in_sizes, int n_in,
                              void* d_out, int out_size, void* d_ws, size_t ws_size,
                              hipStream_t stream) {
  const float* x      = (const float*)d_in[0];
  const int*   y      = (const int*)d_in[1];
  const float* head_w = (const float*)d_in[2];
  const float* head_b = (const float*)d_in[3];
  const float* proj0  = (const float*)d_in[4];
  const float* w0     = (const float*)d_in[5];
  const float* proj1  = (const float*)d_in[6];
  const float* w1     = (const float*)d_in[7];
  float* out = (float*)d_out;

  char* wp = (char*)d_ws;
  unsigned short* xb  = (unsigned short*)wp; wp += (size_t)NROWS * NHID * 2;
  unsigned short* hpb = (unsigned short*)wp; wp += (size_t)HPN * NHID * 2;
  unsigned short* w0b = (unsigned short*)wp; wp += (size_t)TSZ0 * PD0 * 2;
  unsigned short* w1b = (unsigned short*)wp; wp += (size_t)TSZ1 * PD1 * 2;
  unsigned short* hb  = (unsigned short*)wp; wp += (size_t)NROWS * (PD0 + PD1) * 2;
  float* hs = (float*)wp; wp += NROWS * 4;
  float* s0 = (float*)wp; wp += NROWS * 4;
  float* s1 = (float*)wp; wp += NROWS * 4;
  float* ht = (float*)wp; wp += NROWS * 4;
  float* tc = (float*)wp; wp += NROWS * 4;
  int* idx0 = (int*)wp; wp += NROWS * 4;
  int* pos0 = (int*)wp; wp += NROWS * 4;
  int* idx1 = (int*)wp; wp += NROWS * 4;
  int* pos1 = (int*)wp; wp += NROWS * 4;
  int* n01  = (int*)wp; wp += 8 * 4;

  // conv of ALL tensors + compaction + accumulator zeroing
  conv_part<<<dim3(1032), 256, 0, stream>>>(
      x, head_w, proj0, proj1, w0, w1, xb, y,
      idx0, pos0, idx1, pos1, n01, hs, out);

  // proj only (short critical path; sole producer of hb)
  proj_mid<<<dim3(NB_PJ), 256, 0, stream>>>(xb, hpb, hb);

  // fused tail: head (first) + c1 + c0 + target gather, one dispatch
  fused_tail<<<dim3(NB_TAIL), 256, 0, stream>>>(
      hb, w0b, w1b, xb, hpb, head_b, y, idx0, idx1, n01, hs, s0, s1, ht, tc);

  // per-row loss + mean (out[NROWS] pre-zeroed by conv_part)
  rowloss<<<dim3(NROWS / 256), 256, 0, stream>>>(
      hs, ht, s0, s1, tc, pos0, pos1, y, out);
}